// Round 7
// baseline (344.831 us; speedup 1.0000x reference)
//
#include <hip/hip_runtime.h>
#include <hip/hip_bf16.h>
#include <string.h>
#include <stdint.h>

typedef __hip_bfloat16 bf16;

#define FIN 16
#define H   32
#define PADW 64
#define NB  512
#define BINCAP 4096
#define NPBMAX 200
#define PSTRIDE 65
#define CHUNK 2048
#define BINSTRIDE 16
#define SCAN_CHUNK 1024
#define MAXSEG 64
#define POOLBLK 256

typedef int vi4 __attribute__((ext_vector_type(4)));

__device__ __forceinline__ float b2f(bf16 v) { return __bfloat162float(v); }

__device__ __forceinline__ float loadf(const void* p, size_t i, int f32) {
    return f32 ? ((const float*)p)[i] : b2f(((const bf16*)p)[i]);
}
__device__ __forceinline__ void storef(void* p, size_t i, float v, int f32) {
    if (f32) ((float*)p)[i] = v;
    else     ((bf16*)p)[i] = __float2bfloat16(v);
}

__device__ __forceinline__ unsigned pack2(float lo, float hi) {
    bf16 a = __float2bfloat16(lo), b = __float2bfloat16(hi);
    unsigned short ua, ub;
    memcpy(&ua, &a, 2); memcpy(&ub, &b, 2);
    return ((unsigned)ub << 16) | (unsigned)ua;
}
__device__ __forceinline__ float f_lo(unsigned u) {
    union { unsigned i; float f; } v; v.i = u << 16; return v.f;
}
__device__ __forceinline__ float f_hi(unsigned u) {
    union { unsigned i; float f; } v; v.i = u & 0xffff0000u; return v.f;
}

// detect (block 0) + grid-stride zero of small buffers (all blocks)
__global__ void k_detect(const void* __restrict__ x, int nelem, int* __restrict__ flag,
                         float* __restrict__ zf, int nzf,
                         int* __restrict__ zi, int nzi) {
    int gt = blockIdx.x * blockDim.x + threadIdx.x;
    int gs = gridDim.x * blockDim.x;
    for (int i = gt; i < nzf; i += gs) zf[i] = 0.f;
    if (zi) for (int i = gt; i < nzi; i += gs) zi[i] = 0;
    if (blockIdx.x != 0) return;
    __shared__ int cntS;
    if (threadIdx.x == 0) cntS = 0;
    __syncthreads();
    int bad = 0;
    const bf16* p = (const bf16*)x;
    for (int i = threadIdx.x; i < nelem; i += blockDim.x) {
        float v = b2f(p[i]);
        float a = fabsf(v);
        if (isnan(v) || a > 1024.f || (v != 0.f && a < 1e-20f)) bad++;
    }
    atomicAdd(&cntS, bad);
    __syncthreads();
    if (threadIdx.x == 0) flag[0] = (cntS > 64) ? 1 : 0;
}

// ---------- Tier A: direct padded CSR build (single pass) ----------

__global__ void k_fillp(const int* __restrict__ src, const int* __restrict__ dst,
                        int* __restrict__ cursor, int* __restrict__ csr, int E) {
    int e = blockIdx.x * blockDim.x + threadIdx.x;
    if (e >= E) return;
    int d = dst[e];
    int pos = atomicAdd(&cursor[d], 1);
    if (pos < PADW) csr[((size_t)d << 6) + pos] = src[e];
}

__global__ void k_dinvi(const int* __restrict__ deg, float* __restrict__ dinv, int N) {
    int t = blockIdx.x * blockDim.x + threadIdx.x;
    if (t < N) dinv[t] = rsqrtf((float)deg[t] + 1.0f);
}

__global__ void __launch_bounds__(256) k_xw1v(
        const void* __restrict__ x, const void* __restrict__ W1,
        const float* __restrict__ dinv, const int* __restrict__ flag,
        unsigned* __restrict__ xsb, int N) {
    __shared__ float sW[FIN * H];
    __shared__ float sxx[16 * 17];
    int f32 = flag[0];
    for (int i = threadIdx.x; i < FIN * H; i += blockDim.x) sW[i] = loadf(W1, i, f32);
    __syncthreads();
    int t = blockIdx.x * blockDim.x + threadIdx.x;
    int n = t >> 4, j = t & 15, g = threadIdx.x >> 4;
    if (n < N) sxx[g * 17 + j] = loadf(x, (size_t)n * FIN + j, f32);
    __syncthreads();
    if (n >= N) return;
    float dv = dinv[n];
    float s0 = 0.f, s1 = 0.f;
    const float* xp = &sxx[g * 17];
#pragma unroll
    for (int i = 0; i < FIN; i++) {
        float xv = xp[i];
        s0 += xv * sW[i * H + 2 * j];
        s1 += xv * sW[i * H + 2 * j + 1];
    }
    xsb[(size_t)n * 16 + j] = pack2(s0 * dv, s1 * dv);
}

// ---------- Tier A2 (fallback): two-phase binned padded-CSR build ----------
__global__ void __launch_bounds__(1024) k_p1(
        const int* __restrict__ src, const int* __restrict__ dst,
        int* __restrict__ bincur, unsigned* __restrict__ binbuf,
        int E, int npb) {
    __shared__ int hcnt[4][NB];
    __shared__ int hbase[NB];
    __shared__ int scur[NB];
    int tid = threadIdx.x;
    int grp = tid >> 8;
    int e0 = blockIdx.x * CHUNK;
    int nE = E - e0;
    if (nE > CHUNK) nE = CHUNK;
    for (int i = tid; i < 4 * NB; i += blockDim.x) ((int*)hcnt)[i] = 0;
    __syncthreads();
    for (int i = tid; i < nE; i += blockDim.x)
        atomicAdd(&hcnt[grp][dst[e0 + i] / npb], 1);
    __syncthreads();
    for (int i = tid; i < NB; i += blockDim.x) {
        int c = hcnt[0][i] + hcnt[1][i] + hcnt[2][i] + hcnt[3][i];
        hbase[i] = c ? atomicAdd(&bincur[i * BINSTRIDE], c) : 0;
        scur[i] = 0;
    }
    __syncthreads();
    for (int i = tid; i < nE; i += blockDim.x) {
        int d = dst[e0 + i];
        int bin = d / npb;
        int pos = hbase[bin] + atomicAdd(&scur[bin], 1);
        if (pos < BINCAP)
            binbuf[(size_t)bin * BINCAP + pos] =
                ((unsigned)src[e0 + i] << 10) | (unsigned)(d - bin * npb);
    }
}

__global__ void __launch_bounds__(256) k_p2x(
        const int* __restrict__ bincur, const unsigned* __restrict__ binbuf,
        int* __restrict__ csr, int* __restrict__ deg, float* __restrict__ dinv,
        const void* __restrict__ x, const void* __restrict__ W1,
        const int* __restrict__ flag, unsigned* __restrict__ xsb,
        int N, int npb) {
    __shared__ int cur[NPBMAX];
    __shared__ int psr[NPBMAX * PSTRIDE];
    __shared__ float sW1[FIN * H];
    int f32v = flag[0];
    int b = blockIdx.x;
    int base = b * npb;
    int nn = N - base;
    if (nn > npb) nn = npb;
    if (nn < 0) nn = 0;
    for (int i = threadIdx.x; i < FIN * H; i += blockDim.x) sW1[i] = loadf(W1, i, f32v);
    for (int i = threadIdx.x; i < nn; i += blockDim.x) cur[i] = 0;
    __syncthreads();
    int cnt = bincur[b * BINSTRIDE];
    if (cnt > BINCAP) cnt = BINCAP;
    const unsigned* buf = binbuf + (size_t)b * BINCAP;
    for (int j = threadIdx.x; j < cnt; j += blockDim.x) {
        unsigned p = buf[j];
        int loc = (int)(p & 1023u);
        int s = (int)(p >> 10);
        int pos = atomicAdd(&cur[loc], 1);
        if (pos < PADW) psr[loc * PSTRIDE + pos] = s;
    }
    __syncthreads();
    int tot4 = nn * 16;
    for (int idx = threadIdx.x; idx < tot4; idx += blockDim.x) {
        int i = idx >> 4, p4 = (idx & 15) << 2;
        int dg = cur[i];
        if (dg > PADW) dg = PADW;
        if (p4 < dg) {
            const int* pr = &psr[i * PSTRIDE + p4];
            vi4 v = {pr[0], pr[1], pr[2], pr[3]};
            *(vi4*)(csr + ((size_t)(base + i) << 6) + p4) = v;
        }
    }
    for (int i = threadIdx.x; i < nn; i += blockDim.x) {
        int dg = cur[i];
        int n = base + i;
        deg[n] = dg;
        float dv = rsqrtf((float)dg + 1.0f);
        dinv[n] = dv;
        float xr[FIN];
        if (f32v) {
            const float4* xp = (const float4*)((const float*)x + (size_t)n * FIN);
            float4 v0 = xp[0], v1 = xp[1], v2 = xp[2], v3 = xp[3];
            xr[0]=v0.x; xr[1]=v0.y; xr[2]=v0.z; xr[3]=v0.w;
            xr[4]=v1.x; xr[5]=v1.y; xr[6]=v1.z; xr[7]=v1.w;
            xr[8]=v2.x; xr[9]=v2.y; xr[10]=v2.z; xr[11]=v2.w;
            xr[12]=v3.x; xr[13]=v3.y; xr[14]=v3.z; xr[15]=v3.w;
        } else {
            const uint4* xp = (const uint4*)((const bf16*)x + (size_t)n * FIN);
            uint4 u0 = xp[0], u1 = xp[1];
            xr[0]=f_lo(u0.x); xr[1]=f_hi(u0.x); xr[2]=f_lo(u0.y); xr[3]=f_hi(u0.y);
            xr[4]=f_lo(u0.z); xr[5]=f_hi(u0.z); xr[6]=f_lo(u0.w); xr[7]=f_hi(u0.w);
            xr[8]=f_lo(u1.x); xr[9]=f_hi(u1.x); xr[10]=f_lo(u1.y); xr[11]=f_hi(u1.y);
            xr[12]=f_lo(u1.z); xr[13]=f_hi(u1.z); xr[14]=f_lo(u1.w); xr[15]=f_hi(u1.w);
        }
        unsigned outp[16];
#pragma unroll
        for (int jj = 0; jj < 16; jj++) {
            float s0 = 0.f, s1 = 0.f;
#pragma unroll
            for (int f = 0; f < FIN; f++) {
                float xv = xr[f];
                s0 += xv * sW1[f * H + 2 * jj];
                s1 += xv * sW1[f * H + 2 * jj + 1];
            }
            outp[jj] = pack2(s0 * dv, s1 * dv);
        }
        uint4* op = (uint4*)(xsb + (size_t)n * 16);
        op[0] = make_uint4(outp[0], outp[1], outp[2], outp[3]);
        op[1] = make_uint4(outp[4], outp[5], outp[6], outp[7]);
        op[2] = make_uint4(outp[8], outp[9], outp[10], outp[11]);
        op[3] = make_uint4(outp[12], outp[13], outp[14], outp[15]);
    }
}

// 8-wide unrolled neighbor accumulation: 8 independent table loads in flight
#define GACC8(TBL)                                                        \
    for (; k + 8 <= len; k += 8) {                                        \
        vi4 sA = *(const vi4*)(lst + k);                                  \
        vi4 sB = *(const vi4*)(lst + k + 4);                              \
        unsigned u0 = TBL[(size_t)sA.x * 16 + j];                         \
        unsigned u1 = TBL[(size_t)sA.y * 16 + j];                         \
        unsigned u2 = TBL[(size_t)sA.z * 16 + j];                         \
        unsigned u3 = TBL[(size_t)sA.w * 16 + j];                         \
        unsigned u4 = TBL[(size_t)sB.x * 16 + j];                         \
        unsigned u5 = TBL[(size_t)sB.y * 16 + j];                         \
        unsigned u6 = TBL[(size_t)sB.z * 16 + j];                         \
        unsigned u7 = TBL[(size_t)sB.w * 16 + j];                         \
        a0 += f_lo(u0); a1 += f_hi(u0);                                   \
        b0 += f_lo(u1); b1v += f_hi(u1);                                  \
        a0 += f_lo(u2); a1 += f_hi(u2);                                   \
        b0 += f_lo(u3); b1v += f_hi(u3);                                  \
        a0 += f_lo(u4); a1 += f_hi(u4);                                   \
        b0 += f_lo(u5); b1v += f_hi(u5);                                  \
        a0 += f_lo(u6); a1 += f_hi(u6);                                   \
        b0 += f_lo(u7); b1v += f_hi(u7);                                  \
    }                                                                     \
    for (; k + 4 <= len; k += 4) {                                        \
        vi4 s4 = *(const vi4*)(lst + k);                                  \
        unsigned u0 = TBL[(size_t)s4.x * 16 + j];                         \
        unsigned u1 = TBL[(size_t)s4.y * 16 + j];                         \
        unsigned u2 = TBL[(size_t)s4.z * 16 + j];                         \
        unsigned u3 = TBL[(size_t)s4.w * 16 + j];                         \
        a0 += f_lo(u0); a1 += f_hi(u0);                                   \
        b0 += f_lo(u1); b1v += f_hi(u1);                                  \
        a0 += f_lo(u2); a1 += f_hi(u2);                                   \
        b0 += f_lo(u3); b1v += f_hi(u3);                                  \
    }                                                                     \
    for (; k < len; k++) {                                                \
        unsigned u2 = TBL[(size_t)lst[k] * 16 + j];                       \
        a0 += f_lo(u2); a1 += f_hi(u2);                                   \
    }

// fused gather #1
__global__ void __launch_bounds__(256) k_g1(
        const int* __restrict__ deg, const int* __restrict__ csr,
        const float* __restrict__ dinv, const unsigned* __restrict__ xsb,
        const void* __restrict__ W2, const void* __restrict__ b1,
        const int* __restrict__ flag, unsigned* __restrict__ xsb2, int N) {
    __shared__ float sW[H * H];
    __shared__ float sb[H];
    __shared__ float shh[16 * 34];
    int f32 = flag[0];
    for (int i = threadIdx.x; i < H * H; i += blockDim.x) sW[i] = loadf(W2, i, f32);
    if (threadIdx.x < H) sb[threadIdx.x] = loadf(b1, threadIdx.x, f32);
    __syncthreads();
    int t = blockIdx.x * blockDim.x + threadIdx.x;
    int d = t >> 4, j = t & 15, g = threadIdx.x >> 4;
    float dv = 0.f;
    if (d < N) {
        int len = deg[d];
        if (len > PADW) len = PADW;
        dv = dinv[d];
        const int* lst = csr + ((size_t)d << 6);
        unsigned u = xsb[(size_t)d * 16 + j];
        float a0 = f_lo(u), a1 = f_hi(u);
        float b0 = 0.f, b1v = 0.f;
        int k = 0;
        GACC8(xsb)
        float h0 = (a0 + b0) * dv + sb[2 * j];
        float h1 = (a1 + b1v) * dv + sb[2 * j + 1];
        shh[g * 34 + 2 * j]     = h0 > 0.f ? h0 : 0.f;
        shh[g * 34 + 2 * j + 1] = h1 > 0.f ? h1 : 0.f;
    }
    __syncthreads();
    if (d >= N) return;
    float s0 = 0.f, s1 = 0.f;
    const float* hp = &shh[g * 34];
#pragma unroll
    for (int i = 0; i < H; i++) {
        float hv = hp[i];
        s0 += hv * sW[i * H + 2 * j];
        s1 += hv * sW[i * H + 2 * j + 1];
    }
    xsb2[(size_t)d * 16 + j] = pack2(s0 * dv, s1 * dv);
}

// fused gather #2
__global__ void __launch_bounds__(256) k_g2(
        const int* __restrict__ deg, const int* __restrict__ csr,
        const float* __restrict__ dinv, const unsigned* __restrict__ xsb2,
        const void* __restrict__ b2v, const void* __restrict__ Wbil,
        const int* __restrict__ batch, const int* __restrict__ flag,
        float* __restrict__ pooled, float* __restrict__ cnt,
        unsigned* __restrict__ hb, unsigned* __restrict__ gb, int N) {
    __shared__ float sW[H * H];
    __shared__ float sb[H];
    __shared__ float shh[16 * 34];
    __shared__ int   sg[16];
    __shared__ float spool[16 * H];
    __shared__ float scnt[16];
    int f32 = flag[0];
    int tid = threadIdx.x;
    for (int i = tid; i < H * H; i += blockDim.x) sW[i] = loadf(Wbil, i, f32);
    if (tid < H) sb[tid] = loadf(b2v, tid, f32);
    for (int i = tid; i < 16 * H; i += blockDim.x) spool[i] = 0.f;
    if (tid < 16) scnt[tid] = 0.f;
    int blk0 = blockIdx.x * 16;
    int nv = N - blk0;
    if (nv > 16) nv = 16;
    if (tid < nv) sg[tid] = batch[blk0 + tid];
    __syncthreads();
    int d = blk0 + (tid >> 4), j = tid & 15, g = tid >> 4;
    float h0 = 0.f, h1 = 0.f;
    int valid = (g < nv);
    if (valid) {
        int len = deg[d];
        if (len > PADW) len = PADW;
        float dv = dinv[d];
        const int* lst = csr + ((size_t)d << 6);
        unsigned u = xsb2[(size_t)d * 16 + j];
        float a0 = f_lo(u), a1 = f_hi(u);
        float b0 = 0.f, b1v = 0.f;
        int k = 0;
        GACC8(xsb2)
        h0 = (a0 + b0) * dv + sb[2 * j];
        h1 = (a1 + b1v) * dv + sb[2 * j + 1];
        hb[(size_t)d * 16 + j] = pack2(h0, h1);
        shh[g * 34 + 2 * j]     = h0;
        shh[g * 34 + 2 * j + 1] = h1;
    }
    int g0 = sg[0];
    int nseg = sg[nv - 1] - g0 + 1;
    if (valid) {
        int sgn = sg[g];
        if (nseg <= 16) {
            atomicAdd(&spool[(sgn - g0) * H + 2 * j], h0);
            atomicAdd(&spool[(sgn - g0) * H + 2 * j + 1], h1);
            if (j == 0) atomicAdd(&scnt[sgn - g0], 1.f);
        } else {
            atomicAdd(&pooled[(size_t)sgn * H + 2 * j], h0);
            atomicAdd(&pooled[(size_t)sgn * H + 2 * j + 1], h1);
            if (j == 0) atomicAdd(&cnt[sgn], 1.f);
        }
    }
    __syncthreads();
    if (nseg <= 16) {
        for (int i = tid; i < nseg * H; i += blockDim.x) {
            float v = spool[i];
            if (v != 0.f) atomicAdd(&pooled[(size_t)(g0 + (i >> 5)) * H + (i & 31)], v);
        }
        for (int i = tid; i < nseg; i += blockDim.x)
            if (scnt[i] != 0.f) atomicAdd(&cnt[g0 + i], scnt[i]);
    }
    if (!valid) return;
    float s0 = 0.f, s1 = 0.f;
    const float* hp = &shh[g * 34];
#pragma unroll
    for (int i = 0; i < H; i++) {
        float hv = hp[i];
        s0 += hv * sW[i * H + 2 * j];
        s1 += hv * sW[i * H + 2 * j + 1];
    }
    gb[(size_t)d * 16 + j] = pack2(s0, s1);
}

// legacy fused pool (tiers B/C)
__global__ void __launch_bounds__(512) k_poolhb(
        const void* __restrict__ b2v, const void* __restrict__ Wbil,
        const int* __restrict__ batch, const int* __restrict__ flag,
        const float* __restrict__ aggB, float* __restrict__ pooled,
        float* __restrict__ cnt, bf16* __restrict__ hb, bf16* __restrict__ gb,
        int N) {
    __shared__ float sW[H * H];
    __shared__ float sb[H];
    __shared__ float sh[POOLBLK][H];
    __shared__ int   sg[POOLBLK];
    __shared__ float spool[MAXSEG * H];
    __shared__ float scnt[MAXSEG];
    int f32 = flag[0];
    int tid = threadIdx.x;
    for (int i = tid; i < H * H; i += blockDim.x) sW[i] = loadf(Wbil, i, f32);
    if (tid < H) sb[tid] = loadf(b2v, tid, f32);
    int blk0 = blockIdx.x * POOLBLK;
    int nvalid = N - blk0;
    if (nvalid > POOLBLK) nvalid = POOLBLK;
    if (tid < nvalid) sg[tid] = batch[blk0 + tid];
    for (int i = tid; i < MAXSEG * H; i += blockDim.x) spool[i] = 0.f;
    if (tid < MAXSEG) scnt[tid] = 0.f;
    __syncthreads();
    int f = tid & 31, k = tid >> 5;
    for (int r = k; r < nvalid; r += 16) {
        float v = aggB[(size_t)(blk0 + r) * H + f] + sb[f];
        sh[r][f] = v;
        hb[(size_t)(blk0 + r) * H + f] = __float2bfloat16(v);
    }
    __syncthreads();
    int g0 = sg[0];
    int nseg = sg[nvalid - 1] - g0 + 1;
    if (nseg <= MAXSEG) {
        for (int r = k; r < nvalid; r += 16) {
            int gl = sg[r] - g0;
            atomicAdd(&spool[gl * H + f], sh[r][f]);
            if (f == 0) atomicAdd(&scnt[gl], 1.f);
        }
    } else {
        for (int r = k; r < nvalid; r += 16) {
            atomicAdd(&pooled[(size_t)sg[r] * H + f], sh[r][f]);
            if (f == 0) atomicAdd(&cnt[sg[r]], 1.f);
        }
    }
    for (int r = k; r < nvalid; r += 16) {
        float s = 0.f;
#pragma unroll
        for (int i = 0; i < H; i++) s += sh[r][i] * sW[i * H + f];
        gb[(size_t)(blk0 + r) * H + f] = __float2bfloat16(s);
    }
    if (nseg <= MAXSEG) {
        __syncthreads();
        for (int i = tid; i < nseg * H; i += blockDim.x)
            atomicAdd(&pooled[(size_t)(g0 + (i >> 5)) * H + (i & 31)], spool[i]);
        for (int i = tid; i < nseg; i += blockDim.x)
            atomicAdd(&cnt[g0 + i], scnt[i]);
    }
}

// ---------- Tier B: compact CSR via scans (fp32 path) ----------

__global__ void k_degi(const int* __restrict__ dst, int* __restrict__ deg, int E) {
    int t = blockIdx.x * blockDim.x + threadIdx.x;
    if (t < E) atomicAdd(&deg[dst[t]], 1);
}

__global__ void k_scan1(const int* __restrict__ deg, int* __restrict__ partials, int N) {
    __shared__ int sd[256];
    int base = blockIdx.x * SCAN_CHUNK + threadIdx.x * 4;
    int s = 0;
#pragma unroll
    for (int k = 0; k < 4; k++) { int i = base + k; s += (i < N) ? deg[i] : 0; }
    sd[threadIdx.x] = s;
    __syncthreads();
    for (int off = 128; off > 0; off >>= 1) {
        if (threadIdx.x < off) sd[threadIdx.x] += sd[threadIdx.x + off];
        __syncthreads();
    }
    if (threadIdx.x == 0) partials[blockIdx.x] = sd[0];
}

__global__ void k_scan2(const int* __restrict__ partials, int* __restrict__ chunk_off, int B1) {
    __shared__ int sd[256];
    int t = threadIdx.x;
    int lv[4];
    int s = 0;
#pragma unroll
    for (int k = 0; k < 4; k++) { int i = t * 4 + k; lv[k] = (i < B1) ? partials[i] : 0; s += lv[k]; }
    sd[t] = s;
    __syncthreads();
    int inc = s;
    for (int off = 1; off < 256; off <<= 1) {
        int v = (t >= off) ? sd[t - off] : 0;
        __syncthreads();
        sd[t] += v;
        __syncthreads();
    }
    int run = sd[t] - inc;
#pragma unroll
    for (int k = 0; k < 4; k++) { int i = t * 4 + k; if (i < B1) chunk_off[i] = run; run += lv[k]; }
    if (t == 255) chunk_off[B1] = run;
}

__global__ void k_scan3(const int* __restrict__ deg, const int* __restrict__ chunk_off,
                        int* __restrict__ row_ptr, int* __restrict__ cursor,
                        int N, int E) {
    __shared__ int sd[256];
    int t = threadIdx.x;
    int base = blockIdx.x * SCAN_CHUNK + t * 4;
    int lv[4];
    int s = 0;
#pragma unroll
    for (int k = 0; k < 4; k++) { int i = base + k; lv[k] = (i < N) ? deg[i] : 0; s += lv[k]; }
    sd[t] = s;
    __syncthreads();
    int inc = s;
    for (int off = 1; off < 256; off <<= 1) {
        int v = (t >= off) ? sd[t - off] : 0;
        __syncthreads();
        sd[t] += v;
        __syncthreads();
    }
    int run = chunk_off[blockIdx.x] + sd[t] - inc;
#pragma unroll
    for (int k = 0; k < 4; k++) {
        int i = base + k;
        if (i < N) { row_ptr[i] = run; cursor[i] = run; }
        run += lv[k];
    }
    if (blockIdx.x == 0 && t == 0) row_ptr[N] = E;
}

__global__ void k_fill(const int* __restrict__ src, const int* __restrict__ dst,
                       int* __restrict__ cursor, int* __restrict__ csr, int E) {
    int e = blockIdx.x * blockDim.x + threadIdx.x;
    if (e >= E) return;
    int pos = atomicAdd(&cursor[dst[e]], 1);
    csr[pos] = src[e];
}

__global__ void k_gather(const int* __restrict__ row_ptr, const int* __restrict__ csr,
                         const float* __restrict__ dinv, const float* __restrict__ xs,
                         float* __restrict__ agg, int N) {
    int t = blockIdx.x * blockDim.x + threadIdx.x;
    int d = t >> 5, f = t & 31;
    if (d >= N) return;
    int beg = row_ptr[d], end = row_ptr[d + 1];
    float acc  = xs[(size_t)d * H + f];
    float acc2 = 0.f;
    int j = beg;
    for (; j + 1 < end; j += 2) {
        int s0 = csr[j], s1 = csr[j + 1];
        acc  += xs[(size_t)s0 * H + f];
        acc2 += xs[(size_t)s1 * H + f];
    }
    if (j < end) acc += xs[(size_t)csr[j] * H + f];
    agg[(size_t)d * H + f] = (acc + acc2) * dinv[d];
}

__global__ void k_xw1n(const void* __restrict__ x, const void* __restrict__ W1,
                       const float* __restrict__ dinv, const int* __restrict__ flag,
                       float* __restrict__ xs, int N) {
    __shared__ float sW[FIN * H];
    int f32 = flag[0];
    for (int i = threadIdx.x; i < FIN * H; i += blockDim.x) sW[i] = loadf(W1, i, f32);
    __syncthreads();
    int n = blockIdx.x * blockDim.x + threadIdx.x;
    if (n >= N) return;
    float xr[FIN];
#pragma unroll
    for (int i = 0; i < FIN; i++) xr[i] = loadf(x, (size_t)n * FIN + i, f32);
    float dv = dinv[n];
#pragma unroll
    for (int f = 0; f < H; f++) {
        float s = 0.f;
#pragma unroll
        for (int i = 0; i < FIN; i++) s += xr[i] * sW[i * H + f];
        xs[(size_t)n * H + f] = s * dv;
    }
}

__global__ void k_h1xw2n(const void* __restrict__ W2, const void* __restrict__ b1,
                         const float* __restrict__ dinv, const int* __restrict__ flag,
                         const float* __restrict__ agg, float* __restrict__ xs2, int N) {
    __shared__ float sW[H * H];
    __shared__ float sb[H];
    int f32 = flag[0];
    for (int i = threadIdx.x; i < H * H; i += blockDim.x) sW[i] = loadf(W2, i, f32);
    if (threadIdx.x < H) sb[threadIdx.x] = loadf(b1, threadIdx.x, f32);
    __syncthreads();
    int n = blockIdx.x * blockDim.x + threadIdx.x;
    if (n >= N) return;
    float hr[H];
#pragma unroll
    for (int f = 0; f < H; f++) {
        float v = agg[(size_t)n * H + f] + sb[f];
        hr[f] = v > 0.f ? v : 0.f;
    }
    float dv = dinv[n];
#pragma unroll
    for (int f = 0; f < H; f++) {
        float s = 0.f;
#pragma unroll
        for (int i = 0; i < H; i++) s += hr[i] * sW[i * H + f];
        xs2[(size_t)n * H + f] = s * dv;
    }
}

// ---------- Tier C fallback: scatter path ----------

__global__ void k_degf(const int* __restrict__ dst, float* __restrict__ deg, int E) {
    int t = blockIdx.x * blockDim.x + threadIdx.x;
    if (t < E) atomicAdd(&deg[dst[t]], 1.0f);
}
__global__ void k_dinvf(float* __restrict__ deg, int N) {
    int t = blockIdx.x * blockDim.x + threadIdx.x;
    if (t < N) deg[t] = rsqrtf(deg[t] + 1.0f);
}
__global__ void k_xw1o(const void* __restrict__ x, const void* __restrict__ W1,
                       const float* __restrict__ dinv, const int* __restrict__ flag,
                       float* __restrict__ xw, float* __restrict__ agg, int N) {
    __shared__ float sW[FIN * H];
    int f32 = flag[0];
    for (int i = threadIdx.x; i < FIN * H; i += blockDim.x) sW[i] = loadf(W1, i, f32);
    __syncthreads();
    int n = blockIdx.x * blockDim.x + threadIdx.x;
    if (n >= N) return;
    float xr[FIN];
#pragma unroll
    for (int i = 0; i < FIN; i++) xr[i] = loadf(x, (size_t)n * FIN + i, f32);
    float dv = dinv[n], dv2 = dv * dv;
#pragma unroll
    for (int f = 0; f < H; f++) {
        float s = 0.f;
#pragma unroll
        for (int i = 0; i < FIN; i++) s += xr[i] * sW[i * H + f];
        xw[(size_t)n * H + f]  = s;
        agg[(size_t)n * H + f] = s * dv2;
    }
}
__global__ void k_scatter(const int* __restrict__ src, const int* __restrict__ dst,
                          const float* __restrict__ dinv, const float* __restrict__ xw,
                          float* __restrict__ agg, int E) {
    int t = blockIdx.x * blockDim.x + threadIdx.x;
    int e = t >> 5, f = t & 31;
    if (e >= E) return;
    int s = src[e], d = dst[e];
    float c = dinv[s] * dinv[d];
    atomicAdd(&agg[(size_t)d * H + f], xw[(size_t)s * H + f] * c);
}
__global__ void k_h1xw2o(const void* __restrict__ W2, const void* __restrict__ b1,
                         const float* __restrict__ dinv, const int* __restrict__ flag,
                         float* __restrict__ aggio, float* __restrict__ xw2, int N) {
    __shared__ float sW[H * H];
    __shared__ float sb[H];
    int f32 = flag[0];
    for (int i = threadIdx.x; i < H * H; i += blockDim.x) sW[i] = loadf(W2, i, f32);
    if (threadIdx.x < H) sb[threadIdx.x] = loadf(b1, threadIdx.x, f32);
    __syncthreads();
    int n = blockIdx.x * blockDim.x + threadIdx.x;
    if (n >= N) return;
    float hr[H];
#pragma unroll
    for (int f = 0; f < H; f++) {
        float v = aggio[(size_t)n * H + f] + sb[f];
        hr[f] = v > 0.f ? v : 0.f;
    }
    float dv = dinv[n], dv2 = dv * dv;
#pragma unroll
    for (int f = 0; f < H; f++) {
        float s = 0.f;
#pragma unroll
        for (int i = 0; i < H; i++) s += hr[i] * sW[i * H + f];
        xw2[(size_t)n * H + f]   = s;
        aggio[(size_t)n * H + f] = s * dv2;
    }
}

// ---------- output heads: bilinear edges + reg head in one launch ----------

__global__ void k_bilreg(const int* __restrict__ srcA, const int* __restrict__ dstA,
                         const unsigned* __restrict__ gb32, const unsigned* __restrict__ hb32,
                         const void* __restrict__ bbil,
                         const float* __restrict__ pooled, const float* __restrict__ cnt,
                         const void* __restrict__ Wr, const void* __restrict__ br,
                         const int* __restrict__ flag, void* __restrict__ out,
                         int G, int EA) {
    int f32 = flag[0];
    int t = blockIdx.x * blockDim.x + threadIdx.x;
    if (t < EA) {
        int s = srcA[t], d = dstA[t];
        const uint4* gp = (const uint4*)(gb32 + (size_t)s * (H / 2));
        const uint4* hp = (const uint4*)(hb32 + (size_t)d * (H / 2));
        float acc = 0.f;
#pragma unroll
        for (int kk = 0; kk < 4; kk++) {
            uint4 a = gp[kk], b = hp[kk];
            acc += f_lo(a.x) * f_lo(b.x) + f_hi(a.x) * f_hi(b.x);
            acc += f_lo(a.y) * f_lo(b.y) + f_hi(a.y) * f_hi(b.y);
            acc += f_lo(a.z) * f_lo(b.z) + f_hi(a.z) * f_hi(b.z);
            acc += f_lo(a.w) * f_lo(b.w) + f_hi(a.w) * f_hi(b.w);
        }
        storef(out, (size_t)G + t, acc + loadf(bbil, 0, f32), f32);
    } else {
        int g = t - EA;
        if (g < G) {
            float c = cnt[g];
            c = c > 1.f ? c : 1.f;
            float s = 0.f;
#pragma unroll
            for (int i = 0; i < H; i++) s += pooled[(size_t)g * H + i] * loadf(Wr, i, f32);
            storef(out, g, s / c + loadf(br, 0, f32), f32);
        }
    }
}

extern "C" void kernel_launch(void* const* d_in, const int* in_sizes, int n_in,
                              void* d_out, int out_size, void* d_ws, size_t ws_size,
                              hipStream_t stream) {
    const void* x     = d_in[0];
    const int*  ei    = (const int*)d_in[1];
    const int*  eia   = (const int*)d_in[2];
    const int*  batch = (const int*)d_in[3];
    const void* W1    = d_in[4];
    const void* b1    = d_in[5];
    const void* W2    = d_in[6];
    const void* b2    = d_in[7];
    const void* Wr    = d_in[8];
    const void* br    = d_in[9];
    const void* Wbil  = d_in[10];
    const void* bbil  = d_in[11];

    const int N  = in_sizes[0] / FIN;
    const int E  = in_sizes[1] / 2;
    const int EA = in_sizes[2] / 2;
    const int G  = out_size - EA;

    // float region: flag[16] | dinv[N] | A[N*H] | B[N*H] | pooled[G*H] | cnt[G]
    float* ws     = (float*)d_ws;
    int*   flag   = (int*)ws;
    float* dinv   = ws + 16;
    float* A      = dinv + N;
    float* B      = A + (size_t)N * H;
    float* pooled = B + (size_t)N * H;
    float* cnt    = pooled + (size_t)G * H;
    float* fend   = cnt + G;

    // bf16 tables: xsb in B-lo, xsb2 in B-hi; hb/gb in A
    unsigned* xsb  = (unsigned*)B;
    unsigned* xsb2 = (unsigned*)B + (size_t)N * 16;
    unsigned* hb32 = (unsigned*)A;
    unsigned* gb32 = hb32 + (size_t)N * (H / 2);

    // Tier A / A2 int region: deg[N] | csr_pad[N*PADW] (16B-aligned) | bincur[NB*BINSTRIDE]
    int* degA   = (int*)fend;
    int* csrA   = (int*)(((uintptr_t)(degA + N) + 15) & ~(uintptr_t)15);
    int* bincur = csrA + (size_t)N * PADW;
    size_t needA  = (size_t)((char*)bincur - (char*)d_ws);
    size_t needA2 = (size_t)((char*)(bincur + NB * BINSTRIDE) - (char*)d_ws);
    // Tier B int region
    const int B1 = (N + SCAN_CHUNK - 1) / SCAN_CHUNK;
    int* deg_i     = (int*)fend;
    int* curB      = deg_i + N;
    int* row_ptr   = curB + N;
    int* chunk_off = row_ptr + N + 1;
    int* csrB      = chunk_off + B1 + 1;
    size_t needB = (size_t)((char*)(csrB + E) - (char*)d_ws);

    const int npb = (N + NB - 1) / NB;
    // A/B flip (round 7): prefer the single-pass direct build (tier A) over
    // the two-kernel binned build (tier A2). A2 kept as fallback.
    const bool tierA  = (ws_size >= needA);
    const bool tierA2 = !tierA && (ws_size >= needA2) && (npb <= NPBMAX) &&
                        (N <= (1 << 22)) &&
                        ((size_t)NB * BINCAP <= (size_t)N * H * 2);
    const bool tierB  = !tierA2 && !tierA && (ws_size >= needB) && (B1 <= 1024);

    const int* src  = ei;
    const int* dst  = ei + E;
    const int* srcA = eia;
    const int* dstA = eia + EA;

    const int TB = 256;
    const int npool = G * H + G;   // pooled + cnt, contiguous

    // detect + zero pooled/cnt; for tier A also zero the degA cursor array;
    // for tier A2 zero bincur
    k_detect<<<8, 1024, 0, stream>>>(x, 1024, flag, pooled, npool,
                                     tierA ? degA : (tierA2 ? bincur : (int*)nullptr),
                                     tierA ? N : (tierA2 ? NB * BINSTRIDE : 0));

    int ggrid16 = (int)(((long)N * 16 + TB - 1) / TB);
    int ggrid32 = (int)(((long)N * 32 + TB - 1) / TB);
    int ngrid   = (N + TB - 1) / TB;

    if (tierA) {
        k_fillp<<<(E + TB - 1) / TB, TB, 0, stream>>>(src, dst, degA, csrA, E);
        k_dinvi<<<ngrid, TB, 0, stream>>>(degA, dinv, N);
        k_xw1v<<<ggrid16, TB, 0, stream>>>(x, W1, dinv, flag, xsb, N);
        k_g1<<<ggrid16, TB, 0, stream>>>(degA, csrA, dinv, xsb, W2, b1, flag, xsb2, N);
        k_g2<<<ggrid16, TB, 0, stream>>>(degA, csrA, dinv, xsb2, b2, Wbil, batch, flag,
                                         pooled, cnt, hb32, gb32, N);
    } else if (tierA2) {
        unsigned* binbuf = (unsigned*)A;
        int nblk1 = (E + CHUNK - 1) / CHUNK;
        k_p1<<<nblk1, 1024, 0, stream>>>(src, dst, bincur, binbuf, E, npb);
        k_p2x<<<NB, TB, 0, stream>>>(bincur, binbuf, csrA, degA, dinv,
                                     x, W1, flag, xsb, N, npb);
        k_g1<<<ggrid16, TB, 0, stream>>>(degA, csrA, dinv, xsb, W2, b1, flag, xsb2, N);
        k_g2<<<ggrid16, TB, 0, stream>>>(degA, csrA, dinv, xsb2, b2, Wbil, batch, flag,
                                         pooled, cnt, hb32, gb32, N);
    } else if (tierB) {
        hipMemsetAsync(deg_i, 0, (size_t)N * sizeof(int), stream);
        k_degi<<<(E + TB - 1) / TB, TB, 0, stream>>>(dst, deg_i, E);
        k_dinvi<<<ngrid, TB, 0, stream>>>(deg_i, dinv, N);
        k_scan1<<<B1, TB, 0, stream>>>(deg_i, chunk_off, N);
        k_scan2<<<1, TB, 0, stream>>>(chunk_off, chunk_off, B1);
        k_scan3<<<B1, TB, 0, stream>>>(deg_i, chunk_off, row_ptr, curB, N, E);
        k_fill<<<(E + TB - 1) / TB, TB, 0, stream>>>(src, dst, curB, csrB, E);
        k_xw1n<<<ngrid, TB, 0, stream>>>(x, W1, dinv, flag, A, N);
        k_gather<<<ggrid32, TB, 0, stream>>>(row_ptr, csrB, dinv, A, B, N);
        k_h1xw2n<<<ngrid, TB, 0, stream>>>(W2, b1, dinv, flag, B, A, N);
        k_gather<<<ggrid32, TB, 0, stream>>>(row_ptr, csrB, dinv, A, B, N);
        k_poolhb<<<(N + POOLBLK - 1) / POOLBLK, 512, 0, stream>>>(
            b2, Wbil, batch, flag, B, pooled, cnt, (bf16*)hb32, (bf16*)gb32, N);
    } else {
        hipMemsetAsync(dinv, 0, (size_t)N * sizeof(float), stream);
        k_degf<<<(E + TB - 1) / TB, TB, 0, stream>>>(dst, dinv, E);
        k_dinvf<<<ngrid, TB, 0, stream>>>(dinv, N);
        k_xw1o<<<ngrid, TB, 0, stream>>>(x, W1, dinv, flag, A, B, N);
        long tot = (long)E * 32;
        int sgrid = (int)((tot + TB - 1) / TB);
        k_scatter<<<sgrid, TB, 0, stream>>>(src, dst, dinv, A, B, E);
        k_h1xw2o<<<ngrid, TB, 0, stream>>>(W2, b1, dinv, flag, B, A, N);
        k_scatter<<<sgrid, TB, 0, stream>>>(src, dst, dinv, A, B, E);
        k_poolhb<<<(N + POOLBLK - 1) / POOLBLK, 512, 0, stream>>>(
            b2, Wbil, batch, flag, B, pooled, cnt, (bf16*)hb32, (bf16*)gb32, N);
    }

    k_bilreg<<<(EA + G + TB - 1) / TB, TB, 0, stream>>>(
        srcA, dstA, gb32, hb32, bbil, pooled, cnt, Wr, br, flag, d_out, G, EA);
}

// Round 8
// 283.966 us; speedup vs baseline: 1.2143x; 1.2143x over previous
//
#include <hip/hip_runtime.h>
#include <hip/hip_bf16.h>
#include <string.h>
#include <stdint.h>

typedef __hip_bfloat16 bf16;

#define FIN 16
#define H   32
#define PADW 64
#define NB  1024
#define BINCAP 2048
#define NPBMAX 104
#define PSTRIDE 65
#define CHUNK 2048
#define BINSTRIDE 16
#define SCAN_CHUNK 1024
#define MAXSEG 64
#define POOLBLK 256

typedef int vi4 __attribute__((ext_vector_type(4)));

__device__ __forceinline__ float b2f(bf16 v) { return __bfloat162float(v); }

__device__ __forceinline__ float loadf(const void* p, size_t i, int f32) {
    return f32 ? ((const float*)p)[i] : b2f(((const bf16*)p)[i]);
}
__device__ __forceinline__ void storef(void* p, size_t i, float v, int f32) {
    if (f32) ((float*)p)[i] = v;
    else     ((bf16*)p)[i] = __float2bfloat16(v);
}

__device__ __forceinline__ unsigned pack2(float lo, float hi) {
    bf16 a = __float2bfloat16(lo), b = __float2bfloat16(hi);
    unsigned short ua, ub;
    memcpy(&ua, &a, 2); memcpy(&ub, &b, 2);
    return ((unsigned)ub << 16) | (unsigned)ua;
}
__device__ __forceinline__ float f_lo(unsigned u) {
    union { unsigned i; float f; } v; v.i = u << 16; return v.f;
}
__device__ __forceinline__ float f_hi(unsigned u) {
    union { unsigned i; float f; } v; v.i = u & 0xffff0000u; return v.f;
}

// detect (block 0) + grid-stride zero of small buffers (all blocks)
__global__ void k_detect(const void* __restrict__ x, int nelem, int* __restrict__ flag,
                         float* __restrict__ zf, int nzf,
                         int* __restrict__ zi, int nzi) {
    int gt = blockIdx.x * blockDim.x + threadIdx.x;
    int gs = gridDim.x * blockDim.x;
    for (int i = gt; i < nzf; i += gs) zf[i] = 0.f;
    if (zi) for (int i = gt; i < nzi; i += gs) zi[i] = 0;
    if (blockIdx.x != 0) return;
    __shared__ int cntS;
    if (threadIdx.x == 0) cntS = 0;
    __syncthreads();
    int bad = 0;
    const bf16* p = (const bf16*)x;
    for (int i = threadIdx.x; i < nelem; i += blockDim.x) {
        float v = b2f(p[i]);
        float a = fabsf(v);
        if (isnan(v) || a > 1024.f || (v != 0.f && a < 1e-20f)) bad++;
    }
    atomicAdd(&cntS, bad);
    __syncthreads();
    if (threadIdx.x == 0) flag[0] = (cntS > 64) ? 1 : 0;
}

// ---------- Tier A2: two-phase binned padded-CSR build ----------
__global__ void __launch_bounds__(1024) k_p1(
        const int* __restrict__ src, const int* __restrict__ dst,
        int* __restrict__ bincur, unsigned* __restrict__ binbuf,
        int E, int npb) {
    __shared__ int hcnt[4][NB];   // 16 KB
    __shared__ int hbase[NB];
    __shared__ int scur[NB];
    int tid = threadIdx.x;
    int grp = tid >> 8;
    int e0 = blockIdx.x * CHUNK;
    int nE = E - e0;
    if (nE > CHUNK) nE = CHUNK;
    for (int i = tid; i < 4 * NB; i += blockDim.x) ((int*)hcnt)[i] = 0;
    __syncthreads();
    for (int i = tid; i < nE; i += blockDim.x)
        atomicAdd(&hcnt[grp][dst[e0 + i] / npb], 1);
    __syncthreads();
    for (int i = tid; i < NB; i += blockDim.x) {
        int c = hcnt[0][i] + hcnt[1][i] + hcnt[2][i] + hcnt[3][i];
        hbase[i] = c ? atomicAdd(&bincur[i * BINSTRIDE], c) : 0;
        scur[i] = 0;
    }
    __syncthreads();
    for (int i = tid; i < nE; i += blockDim.x) {
        int d = dst[e0 + i];
        int bin = d / npb;
        int pos = hbase[bin] + atomicAdd(&scur[bin], 1);
        if (pos < BINCAP)
            binbuf[(size_t)bin * BINCAP + pos] =
                ((unsigned)src[e0 + i] << 10) | (unsigned)(d - bin * npb);
    }
}

// p2 fused with xw1: build padded CSR rows + deg/dinv, then compute
// xsb = bf16( (x @ W1) * dinv ) for this block's node range.
// NPBMAX=104: psr = 27KB -> ~5 blocks/CU (was 52KB / 3 blocks)
__global__ void __launch_bounds__(256) k_p2x(
        const int* __restrict__ bincur, const unsigned* __restrict__ binbuf,
        int* __restrict__ csr, int* __restrict__ deg, float* __restrict__ dinv,
        const void* __restrict__ x, const void* __restrict__ W1,
        const int* __restrict__ flag, unsigned* __restrict__ xsb,
        int N, int npb) {
    __shared__ int cur[NPBMAX];
    __shared__ int psr[NPBMAX * PSTRIDE];   // ~27 KB
    __shared__ float sW1[FIN * H];          // 2 KB
    int f32v = flag[0];
    int b = blockIdx.x;
    int base = b * npb;
    int nn = N - base;
    if (nn > npb) nn = npb;
    if (nn < 0) nn = 0;
    for (int i = threadIdx.x; i < FIN * H; i += blockDim.x) sW1[i] = loadf(W1, i, f32v);
    for (int i = threadIdx.x; i < nn; i += blockDim.x) cur[i] = 0;
    __syncthreads();
    int cnt = bincur[b * BINSTRIDE];
    if (cnt > BINCAP) cnt = BINCAP;
    const unsigned* buf = binbuf + (size_t)b * BINCAP;
    for (int j = threadIdx.x; j < cnt; j += blockDim.x) {
        unsigned p = buf[j];
        int loc = (int)(p & 1023u);
        int s = (int)(p >> 10);
        int pos = atomicAdd(&cur[loc], 1);
        if (pos < PADW) psr[loc * PSTRIDE + pos] = s;
    }
    __syncthreads();
    // vectorized CSR store: int4 chunks; positions >= deg are garbage but
    // never read (gather clamps to deg)
    int tot4 = nn * 16;
    for (int idx = threadIdx.x; idx < tot4; idx += blockDim.x) {
        int i = idx >> 4, p4 = (idx & 15) << 2;
        int dg = cur[i];
        if (dg > PADW) dg = PADW;
        if (p4 < dg) {
            const int* pr = &psr[i * PSTRIDE + p4];
            vi4 v = {pr[0], pr[1], pr[2], pr[3]};
            *(vi4*)(csr + ((size_t)(base + i) << 6) + p4) = v;
        }
    }
    // deg/dinv + fused xw1 for this node range
    for (int i = threadIdx.x; i < nn; i += blockDim.x) {
        int dg = cur[i];
        int n = base + i;
        deg[n] = dg;
        float dv = rsqrtf((float)dg + 1.0f);
        dinv[n] = dv;
        float xr[FIN];
        if (f32v) {
            const float4* xp = (const float4*)((const float*)x + (size_t)n * FIN);
            float4 v0 = xp[0], v1 = xp[1], v2 = xp[2], v3 = xp[3];
            xr[0]=v0.x; xr[1]=v0.y; xr[2]=v0.z; xr[3]=v0.w;
            xr[4]=v1.x; xr[5]=v1.y; xr[6]=v1.z; xr[7]=v1.w;
            xr[8]=v2.x; xr[9]=v2.y; xr[10]=v2.z; xr[11]=v2.w;
            xr[12]=v3.x; xr[13]=v3.y; xr[14]=v3.z; xr[15]=v3.w;
        } else {
            const uint4* xp = (const uint4*)((const bf16*)x + (size_t)n * FIN);
            uint4 u0 = xp[0], u1 = xp[1];
            xr[0]=f_lo(u0.x); xr[1]=f_hi(u0.x); xr[2]=f_lo(u0.y); xr[3]=f_hi(u0.y);
            xr[4]=f_lo(u0.z); xr[5]=f_hi(u0.z); xr[6]=f_lo(u0.w); xr[7]=f_hi(u0.w);
            xr[8]=f_lo(u1.x); xr[9]=f_hi(u1.x); xr[10]=f_lo(u1.y); xr[11]=f_hi(u1.y);
            xr[12]=f_lo(u1.z); xr[13]=f_hi(u1.z); xr[14]=f_lo(u1.w); xr[15]=f_hi(u1.w);
        }
        unsigned outp[16];
#pragma unroll
        for (int jj = 0; jj < 16; jj++) {
            float s0 = 0.f, s1 = 0.f;
#pragma unroll
            for (int f = 0; f < FIN; f++) {
                float xv = xr[f];
                s0 += xv * sW1[f * H + 2 * jj];
                s1 += xv * sW1[f * H + 2 * jj + 1];
            }
            outp[jj] = pack2(s0 * dv, s1 * dv);
        }
        uint4* op = (uint4*)(xsb + (size_t)n * 16);
        op[0] = make_uint4(outp[0], outp[1], outp[2], outp[3]);
        op[1] = make_uint4(outp[4], outp[5], outp[6], outp[7]);
        op[2] = make_uint4(outp[8], outp[9], outp[10], outp[11]);
        op[3] = make_uint4(outp[12], outp[13], outp[14], outp[15]);
    }
}

// ---------- Tier A: direct padded CSR (fallback build; known slow) ----------

__global__ void k_fillp(const int* __restrict__ src, const int* __restrict__ dst,
                        int* __restrict__ cursor, int* __restrict__ csr, int E) {
    int e = blockIdx.x * blockDim.x + threadIdx.x;
    if (e >= E) return;
    int d = dst[e];
    int pos = atomicAdd(&cursor[d], 1);
    if (pos < PADW) csr[((size_t)d << 6) + pos] = src[e];
}

__global__ void k_dinvi(const int* __restrict__ deg, float* __restrict__ dinv, int N) {
    int t = blockIdx.x * blockDim.x + threadIdx.x;
    if (t < N) dinv[t] = rsqrtf((float)deg[t] + 1.0f);
}

__global__ void __launch_bounds__(256) k_xw1v(
        const void* __restrict__ x, const void* __restrict__ W1,
        const float* __restrict__ dinv, const int* __restrict__ flag,
        unsigned* __restrict__ xsb, int N) {
    __shared__ float sW[FIN * H];
    __shared__ float sxx[16 * 17];
    int f32 = flag[0];
    for (int i = threadIdx.x; i < FIN * H; i += blockDim.x) sW[i] = loadf(W1, i, f32);
    __syncthreads();
    int t = blockIdx.x * blockDim.x + threadIdx.x;
    int n = t >> 4, j = t & 15, g = threadIdx.x >> 4;
    if (n < N) sxx[g * 17 + j] = loadf(x, (size_t)n * FIN + j, f32);
    __syncthreads();
    if (n >= N) return;
    float dv = dinv[n];
    float s0 = 0.f, s1 = 0.f;
    const float* xp = &sxx[g * 17];
#pragma unroll
    for (int i = 0; i < FIN; i++) {
        float xv = xp[i];
        s0 += xv * sW[i * H + 2 * j];
        s1 += xv * sW[i * H + 2 * j + 1];
    }
    xsb[(size_t)n * 16 + j] = pack2(s0 * dv, s1 * dv);
}

// 8-wide unrolled neighbor accumulation: 8 independent table loads in flight
#define GACC8(TBL)                                                        \
    for (; k + 8 <= len; k += 8) {                                        \
        vi4 sA = *(const vi4*)(lst + k);                                  \
        vi4 sB = *(const vi4*)(lst + k + 4);                              \
        unsigned u0 = TBL[(size_t)sA.x * 16 + j];                         \
        unsigned u1 = TBL[(size_t)sA.y * 16 + j];                         \
        unsigned u2 = TBL[(size_t)sA.z * 16 + j];                         \
        unsigned u3 = TBL[(size_t)sA.w * 16 + j];                         \
        unsigned u4 = TBL[(size_t)sB.x * 16 + j];                         \
        unsigned u5 = TBL[(size_t)sB.y * 16 + j];                         \
        unsigned u6 = TBL[(size_t)sB.z * 16 + j];                         \
        unsigned u7 = TBL[(size_t)sB.w * 16 + j];                         \
        a0 += f_lo(u0); a1 += f_hi(u0);                                   \
        b0 += f_lo(u1); b1v += f_hi(u1);                                  \
        a0 += f_lo(u2); a1 += f_hi(u2);                                   \
        b0 += f_lo(u3); b1v += f_hi(u3);                                  \
        a0 += f_lo(u4); a1 += f_hi(u4);                                   \
        b0 += f_lo(u5); b1v += f_hi(u5);                                  \
        a0 += f_lo(u6); a1 += f_hi(u6);                                   \
        b0 += f_lo(u7); b1v += f_hi(u7);                                  \
    }                                                                     \
    for (; k + 4 <= len; k += 4) {                                        \
        vi4 s4 = *(const vi4*)(lst + k);                                  \
        unsigned u0 = TBL[(size_t)s4.x * 16 + j];                         \
        unsigned u1 = TBL[(size_t)s4.y * 16 + j];                         \
        unsigned u2 = TBL[(size_t)s4.z * 16 + j];                         \
        unsigned u3 = TBL[(size_t)s4.w * 16 + j];                         \
        a0 += f_lo(u0); a1 += f_hi(u0);                                   \
        b0 += f_lo(u1); b1v += f_hi(u1);                                  \
        a0 += f_lo(u2); a1 += f_hi(u2);                                   \
        b0 += f_lo(u3); b1v += f_hi(u3);                                  \
    }                                                                     \
    for (; k < len; k++) {                                                \
        unsigned u2 = TBL[(size_t)lst[k] * 16 + j];                       \
        a0 += f_lo(u2); a1 += f_hi(u2);                                   \
    }

// fused gather #1
__global__ void __launch_bounds__(256) k_g1(
        const int* __restrict__ deg, const int* __restrict__ csr,
        const float* __restrict__ dinv, const unsigned* __restrict__ xsb,
        const void* __restrict__ W2, const void* __restrict__ b1,
        const int* __restrict__ flag, unsigned* __restrict__ xsb2, int N) {
    __shared__ float sW[H * H];
    __shared__ float sb[H];
    __shared__ float shh[16 * 34];
    int f32 = flag[0];
    for (int i = threadIdx.x; i < H * H; i += blockDim.x) sW[i] = loadf(W2, i, f32);
    if (threadIdx.x < H) sb[threadIdx.x] = loadf(b1, threadIdx.x, f32);
    __syncthreads();
    int t = blockIdx.x * blockDim.x + threadIdx.x;
    int d = t >> 4, j = t & 15, g = threadIdx.x >> 4;
    float dv = 0.f;
    if (d < N) {
        int len = deg[d];
        if (len > PADW) len = PADW;
        dv = dinv[d];
        const int* lst = csr + ((size_t)d << 6);
        unsigned u = xsb[(size_t)d * 16 + j];
        float a0 = f_lo(u), a1 = f_hi(u);
        float b0 = 0.f, b1v = 0.f;
        int k = 0;
        GACC8(xsb)
        float h0 = (a0 + b0) * dv + sb[2 * j];
        float h1 = (a1 + b1v) * dv + sb[2 * j + 1];
        shh[g * 34 + 2 * j]     = h0 > 0.f ? h0 : 0.f;
        shh[g * 34 + 2 * j + 1] = h1 > 0.f ? h1 : 0.f;
    }
    __syncthreads();
    if (d >= N) return;
    float s0 = 0.f, s1 = 0.f;
    const float* hp = &shh[g * 34];
#pragma unroll
    for (int i = 0; i < H; i++) {
        float hv = hp[i];
        s0 += hv * sW[i * H + 2 * j];
        s1 += hv * sW[i * H + 2 * j + 1];
    }
    xsb2[(size_t)d * 16 + j] = pack2(s0 * dv, s1 * dv);
}

// fused gather #2
__global__ void __launch_bounds__(256) k_g2(
        const int* __restrict__ deg, const int* __restrict__ csr,
        const float* __restrict__ dinv, const unsigned* __restrict__ xsb2,
        const void* __restrict__ b2v, const void* __restrict__ Wbil,
        const int* __restrict__ batch, const int* __restrict__ flag,
        float* __restrict__ pooled, float* __restrict__ cnt,
        unsigned* __restrict__ hb, unsigned* __restrict__ gb, int N) {
    __shared__ float sW[H * H];
    __shared__ float sb[H];
    __shared__ float shh[16 * 34];
    __shared__ int   sg[16];
    __shared__ float spool[16 * H];
    __shared__ float scnt[16];
    int f32 = flag[0];
    int tid = threadIdx.x;
    for (int i = tid; i < H * H; i += blockDim.x) sW[i] = loadf(Wbil, i, f32);
    if (tid < H) sb[tid] = loadf(b2v, tid, f32);
    for (int i = tid; i < 16 * H; i += blockDim.x) spool[i] = 0.f;
    if (tid < 16) scnt[tid] = 0.f;
    int blk0 = blockIdx.x * 16;
    int nv = N - blk0;
    if (nv > 16) nv = 16;
    if (tid < nv) sg[tid] = batch[blk0 + tid];
    __syncthreads();
    int d = blk0 + (tid >> 4), j = tid & 15, g = tid >> 4;
    float h0 = 0.f, h1 = 0.f;
    int valid = (g < nv);
    if (valid) {
        int len = deg[d];
        if (len > PADW) len = PADW;
        float dv = dinv[d];
        const int* lst = csr + ((size_t)d << 6);
        unsigned u = xsb2[(size_t)d * 16 + j];
        float a0 = f_lo(u), a1 = f_hi(u);
        float b0 = 0.f, b1v = 0.f;
        int k = 0;
        GACC8(xsb2)
        h0 = (a0 + b0) * dv + sb[2 * j];
        h1 = (a1 + b1v) * dv + sb[2 * j + 1];
        hb[(size_t)d * 16 + j] = pack2(h0, h1);
        shh[g * 34 + 2 * j]     = h0;
        shh[g * 34 + 2 * j + 1] = h1;
    }
    int g0 = sg[0];
    int nseg = sg[nv - 1] - g0 + 1;
    if (valid) {
        int sgn = sg[g];
        if (nseg <= 16) {
            atomicAdd(&spool[(sgn - g0) * H + 2 * j], h0);
            atomicAdd(&spool[(sgn - g0) * H + 2 * j + 1], h1);
            if (j == 0) atomicAdd(&scnt[sgn - g0], 1.f);
        } else {
            atomicAdd(&pooled[(size_t)sgn * H + 2 * j], h0);
            atomicAdd(&pooled[(size_t)sgn * H + 2 * j + 1], h1);
            if (j == 0) atomicAdd(&cnt[sgn], 1.f);
        }
    }
    __syncthreads();
    if (nseg <= 16) {
        for (int i = tid; i < nseg * H; i += blockDim.x) {
            float v = spool[i];
            if (v != 0.f) atomicAdd(&pooled[(size_t)(g0 + (i >> 5)) * H + (i & 31)], v);
        }
        for (int i = tid; i < nseg; i += blockDim.x)
            if (scnt[i] != 0.f) atomicAdd(&cnt[g0 + i], scnt[i]);
    }
    if (!valid) return;
    float s0 = 0.f, s1 = 0.f;
    const float* hp = &shh[g * 34];
#pragma unroll
    for (int i = 0; i < H; i++) {
        float hv = hp[i];
        s0 += hv * sW[i * H + 2 * j];
        s1 += hv * sW[i * H + 2 * j + 1];
    }
    gb[(size_t)d * 16 + j] = pack2(s0, s1);
}

// legacy fused pool (tiers B/C)
__global__ void __launch_bounds__(512) k_poolhb(
        const void* __restrict__ b2v, const void* __restrict__ Wbil,
        const int* __restrict__ batch, const int* __restrict__ flag,
        const float* __restrict__ aggB, float* __restrict__ pooled,
        float* __restrict__ cnt, bf16* __restrict__ hb, bf16* __restrict__ gb,
        int N) {
    __shared__ float sW[H * H];
    __shared__ float sb[H];
    __shared__ float sh[POOLBLK][H];
    __shared__ int   sg[POOLBLK];
    __shared__ float spool[MAXSEG * H];
    __shared__ float scnt[MAXSEG];
    int f32 = flag[0];
    int tid = threadIdx.x;
    for (int i = tid; i < H * H; i += blockDim.x) sW[i] = loadf(Wbil, i, f32);
    if (tid < H) sb[tid] = loadf(b2v, tid, f32);
    int blk0 = blockIdx.x * POOLBLK;
    int nvalid = N - blk0;
    if (nvalid > POOLBLK) nvalid = POOLBLK;
    if (tid < nvalid) sg[tid] = batch[blk0 + tid];
    for (int i = tid; i < MAXSEG * H; i += blockDim.x) spool[i] = 0.f;
    if (tid < MAXSEG) scnt[tid] = 0.f;
    __syncthreads();
    int f = tid & 31, k = tid >> 5;
    for (int r = k; r < nvalid; r += 16) {
        float v = aggB[(size_t)(blk0 + r) * H + f] + sb[f];
        sh[r][f] = v;
        hb[(size_t)(blk0 + r) * H + f] = __float2bfloat16(v);
    }
    __syncthreads();
    int g0 = sg[0];
    int nseg = sg[nvalid - 1] - g0 + 1;
    if (nseg <= MAXSEG) {
        for (int r = k; r < nvalid; r += 16) {
            int gl = sg[r] - g0;
            atomicAdd(&spool[gl * H + f], sh[r][f]);
            if (f == 0) atomicAdd(&scnt[gl], 1.f);
        }
    } else {
        for (int r = k; r < nvalid; r += 16) {
            atomicAdd(&pooled[(size_t)sg[r] * H + f], sh[r][f]);
            if (f == 0) atomicAdd(&cnt[sg[r]], 1.f);
        }
    }
    for (int r = k; r < nvalid; r += 16) {
        float s = 0.f;
#pragma unroll
        for (int i = 0; i < H; i++) s += sh[r][i] * sW[i * H + f];
        gb[(size_t)(blk0 + r) * H + f] = __float2bfloat16(s);
    }
    if (nseg <= MAXSEG) {
        __syncthreads();
        for (int i = tid; i < nseg * H; i += blockDim.x)
            atomicAdd(&pooled[(size_t)(g0 + (i >> 5)) * H + (i & 31)], spool[i]);
        for (int i = tid; i < nseg; i += blockDim.x)
            atomicAdd(&cnt[g0 + i], scnt[i]);
    }
}

// ---------- Tier B: compact CSR via scans (fp32 path) ----------

__global__ void k_degi(const int* __restrict__ dst, int* __restrict__ deg, int E) {
    int t = blockIdx.x * blockDim.x + threadIdx.x;
    if (t < E) atomicAdd(&deg[dst[t]], 1);
}

__global__ void k_scan1(const int* __restrict__ deg, int* __restrict__ partials, int N) {
    __shared__ int sd[256];
    int base = blockIdx.x * SCAN_CHUNK + threadIdx.x * 4;
    int s = 0;
#pragma unroll
    for (int k = 0; k < 4; k++) { int i = base + k; s += (i < N) ? deg[i] : 0; }
    sd[threadIdx.x] = s;
    __syncthreads();
    for (int off = 128; off > 0; off >>= 1) {
        if (threadIdx.x < off) sd[threadIdx.x] += sd[threadIdx.x + off];
        __syncthreads();
    }
    if (threadIdx.x == 0) partials[blockIdx.x] = sd[0];
}

__global__ void k_scan2(const int* __restrict__ partials, int* __restrict__ chunk_off, int B1) {
    __shared__ int sd[256];
    int t = threadIdx.x;
    int lv[4];
    int s = 0;
#pragma unroll
    for (int k = 0; k < 4; k++) { int i = t * 4 + k; lv[k] = (i < B1) ? partials[i] : 0; s += lv[k]; }
    sd[t] = s;
    __syncthreads();
    int inc = s;
    for (int off = 1; off < 256; off <<= 1) {
        int v = (t >= off) ? sd[t - off] : 0;
        __syncthreads();
        sd[t] += v;
        __syncthreads();
    }
    int run = sd[t] - inc;
#pragma unroll
    for (int k = 0; k < 4; k++) { int i = t * 4 + k; if (i < B1) chunk_off[i] = run; run += lv[k]; }
    if (t == 255) chunk_off[B1] = run;
}

__global__ void k_scan3(const int* __restrict__ deg, const int* __restrict__ chunk_off,
                        int* __restrict__ row_ptr, int* __restrict__ cursor,
                        int N, int E) {
    __shared__ int sd[256];
    int t = threadIdx.x;
    int base = blockIdx.x * SCAN_CHUNK + t * 4;
    int lv[4];
    int s = 0;
#pragma unroll
    for (int k = 0; k < 4; k++) { int i = base + k; lv[k] = (i < N) ? deg[i] : 0; s += lv[k]; }
    sd[t] = s;
    __syncthreads();
    int inc = s;
    for (int off = 1; off < 256; off <<= 1) {
        int v = (t >= off) ? sd[t - off] : 0;
        __syncthreads();
        sd[t] += v;
        __syncthreads();
    }
    int run = chunk_off[blockIdx.x] + sd[t] - inc;
#pragma unroll
    for (int k = 0; k < 4; k++) {
        int i = base + k;
        if (i < N) { row_ptr[i] = run; cursor[i] = run; }
        run += lv[k];
    }
    if (blockIdx.x == 0 && t == 0) row_ptr[N] = E;
}

__global__ void k_fill(const int* __restrict__ src, const int* __restrict__ dst,
                       int* __restrict__ cursor, int* __restrict__ csr, int E) {
    int e = blockIdx.x * blockDim.x + threadIdx.x;
    if (e >= E) return;
    int pos = atomicAdd(&cursor[dst[e]], 1);
    csr[pos] = src[e];
}

__global__ void k_gather(const int* __restrict__ row_ptr, const int* __restrict__ csr,
                         const float* __restrict__ dinv, const float* __restrict__ xs,
                         float* __restrict__ agg, int N) {
    int t = blockIdx.x * blockDim.x + threadIdx.x;
    int d = t >> 5, f = t & 31;
    if (d >= N) return;
    int beg = row_ptr[d], end = row_ptr[d + 1];
    float acc  = xs[(size_t)d * H + f];
    float acc2 = 0.f;
    int j = beg;
    for (; j + 1 < end; j += 2) {
        int s0 = csr[j], s1 = csr[j + 1];
        acc  += xs[(size_t)s0 * H + f];
        acc2 += xs[(size_t)s1 * H + f];
    }
    if (j < end) acc += xs[(size_t)csr[j] * H + f];
    agg[(size_t)d * H + f] = (acc + acc2) * dinv[d];
}

__global__ void k_xw1n(const void* __restrict__ x, const void* __restrict__ W1,
                       const float* __restrict__ dinv, const int* __restrict__ flag,
                       float* __restrict__ xs, int N) {
    __shared__ float sW[FIN * H];
    int f32 = flag[0];
    for (int i = threadIdx.x; i < FIN * H; i += blockDim.x) sW[i] = loadf(W1, i, f32);
    __syncthreads();
    int n = blockIdx.x * blockDim.x + threadIdx.x;
    if (n >= N) return;
    float xr[FIN];
#pragma unroll
    for (int i = 0; i < FIN; i++) xr[i] = loadf(x, (size_t)n * FIN + i, f32);
    float dv = dinv[n];
#pragma unroll
    for (int f = 0; f < H; f++) {
        float s = 0.f;
#pragma unroll
        for (int i = 0; i < FIN; i++) s += xr[i] * sW[i * H + f];
        xs[(size_t)n * H + f] = s * dv;
    }
}

__global__ void k_h1xw2n(const void* __restrict__ W2, const void* __restrict__ b1,
                         const float* __restrict__ dinv, const int* __restrict__ flag,
                         const float* __restrict__ agg, float* __restrict__ xs2, int N) {
    __shared__ float sW[H * H];
    __shared__ float sb[H];
    int f32 = flag[0];
    for (int i = threadIdx.x; i < H * H; i += blockDim.x) sW[i] = loadf(W2, i, f32);
    if (threadIdx.x < H) sb[threadIdx.x] = loadf(b1, threadIdx.x, f32);
    __syncthreads();
    int n = blockIdx.x * blockDim.x + threadIdx.x;
    if (n >= N) return;
    float hr[H];
#pragma unroll
    for (int f = 0; f < H; f++) {
        float v = agg[(size_t)n * H + f] + sb[f];
        hr[f] = v > 0.f ? v : 0.f;
    }
    float dv = dinv[n];
#pragma unroll
    for (int f = 0; f < H; f++) {
        float s = 0.f;
#pragma unroll
        for (int i = 0; i < H; i++) s += hr[i] * sW[i * H + f];
        xs2[(size_t)n * H + f] = s * dv;
    }
}

// ---------- Tier C fallback: scatter path ----------

__global__ void k_degf(const int* __restrict__ dst, float* __restrict__ deg, int E) {
    int t = blockIdx.x * blockDim.x + threadIdx.x;
    if (t < E) atomicAdd(&deg[dst[t]], 1.0f);
}
__global__ void k_dinvf(float* __restrict__ deg, int N) {
    int t = blockIdx.x * blockDim.x + threadIdx.x;
    if (t < N) deg[t] = rsqrtf(deg[t] + 1.0f);
}
__global__ void k_xw1o(const void* __restrict__ x, const void* __restrict__ W1,
                       const float* __restrict__ dinv, const int* __restrict__ flag,
                       float* __restrict__ xw, float* __restrict__ agg, int N) {
    __shared__ float sW[FIN * H];
    int f32 = flag[0];
    for (int i = threadIdx.x; i < FIN * H; i += blockDim.x) sW[i] = loadf(W1, i, f32);
    __syncthreads();
    int n = blockIdx.x * blockDim.x + threadIdx.x;
    if (n >= N) return;
    float xr[FIN];
#pragma unroll
    for (int i = 0; i < FIN; i++) xr[i] = loadf(x, (size_t)n * FIN + i, f32);
    float dv = dinv[n], dv2 = dv * dv;
#pragma unroll
    for (int f = 0; f < H; f++) {
        float s = 0.f;
#pragma unroll
        for (int i = 0; i < FIN; i++) s += xr[i] * sW[i * H + f];
        xw[(size_t)n * H + f]  = s;
        agg[(size_t)n * H + f] = s * dv2;
    }
}
__global__ void k_scatter(const int* __restrict__ src, const int* __restrict__ dst,
                          const float* __restrict__ dinv, const float* __restrict__ xw,
                          float* __restrict__ agg, int E) {
    int t = blockIdx.x * blockDim.x + threadIdx.x;
    int e = t >> 5, f = t & 31;
    if (e >= E) return;
    int s = src[e], d = dst[e];
    float c = dinv[s] * dinv[d];
    atomicAdd(&agg[(size_t)d * H + f], xw[(size_t)s * H + f] * c);
}
__global__ void k_h1xw2o(const void* __restrict__ W2, const void* __restrict__ b1,
                         const float* __restrict__ dinv, const int* __restrict__ flag,
                         float* __restrict__ aggio, float* __restrict__ xw2, int N) {
    __shared__ float sW[H * H];
    __shared__ float sb[H];
    int f32 = flag[0];
    for (int i = threadIdx.x; i < H * H; i += blockDim.x) sW[i] = loadf(W2, i, f32);
    if (threadIdx.x < H) sb[threadIdx.x] = loadf(b1, threadIdx.x, f32);
    __syncthreads();
    int n = blockIdx.x * blockDim.x + threadIdx.x;
    if (n >= N) return;
    float hr[H];
#pragma unroll
    for (int f = 0; f < H; f++) {
        float v = aggio[(size_t)n * H + f] + sb[f];
        hr[f] = v > 0.f ? v : 0.f;
    }
    float dv = dinv[n], dv2 = dv * dv;
#pragma unroll
    for (int f = 0; f < H; f++) {
        float s = 0.f;
#pragma unroll
        for (int i = 0; i < H; i++) s += hr[i] * sW[i * H + f];
        xw2[(size_t)n * H + f]   = s;
        aggio[(size_t)n * H + f] = s * dv2;
    }
}

// ---------- output heads: bilinear edges + reg head in one launch ----------

__global__ void k_bilreg(const int* __restrict__ srcA, const int* __restrict__ dstA,
                         const unsigned* __restrict__ gb32, const unsigned* __restrict__ hb32,
                         const void* __restrict__ bbil,
                         const float* __restrict__ pooled, const float* __restrict__ cnt,
                         const void* __restrict__ Wr, const void* __restrict__ br,
                         const int* __restrict__ flag, void* __restrict__ out,
                         int G, int EA) {
    int f32 = flag[0];
    int t = blockIdx.x * blockDim.x + threadIdx.x;
    if (t < EA) {
        int s = srcA[t], d = dstA[t];
        const uint4* gp = (const uint4*)(gb32 + (size_t)s * (H / 2));
        const uint4* hp = (const uint4*)(hb32 + (size_t)d * (H / 2));
        float acc = 0.f;
#pragma unroll
        for (int kk = 0; kk < 4; kk++) {
            uint4 a = gp[kk], b = hp[kk];
            acc += f_lo(a.x) * f_lo(b.x) + f_hi(a.x) * f_hi(b.x);
            acc += f_lo(a.y) * f_lo(b.y) + f_hi(a.y) * f_hi(b.y);
            acc += f_lo(a.z) * f_lo(b.z) + f_hi(a.z) * f_hi(b.z);
            acc += f_lo(a.w) * f_lo(b.w) + f_hi(a.w) * f_hi(b.w);
        }
        storef(out, (size_t)G + t, acc + loadf(bbil, 0, f32), f32);
    } else {
        int g = t - EA;
        if (g < G) {
            float c = cnt[g];
            c = c > 1.f ? c : 1.f;
            float s = 0.f;
#pragma unroll
            for (int i = 0; i < H; i++) s += pooled[(size_t)g * H + i] * loadf(Wr, i, f32);
            storef(out, g, s / c + loadf(br, 0, f32), f32);
        }
    }
}

extern "C" void kernel_launch(void* const* d_in, const int* in_sizes, int n_in,
                              void* d_out, int out_size, void* d_ws, size_t ws_size,
                              hipStream_t stream) {
    const void* x     = d_in[0];
    const int*  ei    = (const int*)d_in[1];
    const int*  eia   = (const int*)d_in[2];
    const int*  batch = (const int*)d_in[3];
    const void* W1    = d_in[4];
    const void* b1    = d_in[5];
    const void* W2    = d_in[6];
    const void* b2    = d_in[7];
    const void* Wr    = d_in[8];
    const void* br    = d_in[9];
    const void* Wbil  = d_in[10];
    const void* bbil  = d_in[11];

    const int N  = in_sizes[0] / FIN;
    const int E  = in_sizes[1] / 2;
    const int EA = in_sizes[2] / 2;
    const int G  = out_size - EA;

    // float region: flag[16] | dinv[N] | A[N*H] | B[N*H] | pooled[G*H] | cnt[G]
    float* ws     = (float*)d_ws;
    int*   flag   = (int*)ws;
    float* dinv   = ws + 16;
    float* A      = dinv + N;
    float* B      = A + (size_t)N * H;
    float* pooled = B + (size_t)N * H;
    float* cnt    = pooled + (size_t)G * H;
    float* fend   = cnt + G;

    // bf16 tables: xsb in B-lo, xsb2 in B-hi; hb/gb in A (binbuf space, dead)
    unsigned* xsb  = (unsigned*)B;
    unsigned* xsb2 = (unsigned*)B + (size_t)N * 16;
    unsigned* hb32 = (unsigned*)A;
    unsigned* gb32 = hb32 + (size_t)N * (H / 2);

    // Tier A / A2 int region: deg[N] | csr_pad[N*PADW] (16B-aligned) | bincur[NB*BINSTRIDE]
    int* degA   = (int*)fend;
    int* csrA   = (int*)(((uintptr_t)(degA + N) + 15) & ~(uintptr_t)15);
    int* bincur = csrA + (size_t)N * PADW;
    size_t needA  = (size_t)((char*)bincur - (char*)d_ws);
    size_t needA2 = (size_t)((char*)(bincur + NB * BINSTRIDE) - (char*)d_ws);
    // Tier B int region
    const int B1 = (N + SCAN_CHUNK - 1) / SCAN_CHUNK;
    int* deg_i     = (int*)fend;
    int* curB      = deg_i + N;
    int* row_ptr   = curB + N;
    int* chunk_off = row_ptr + N + 1;
    int* csrB      = chunk_off + B1 + 1;
    size_t needB = (size_t)((char*)(csrB + E) - (char*)d_ws);

    const int npb = (N + NB - 1) / NB;
    // Tier A2 (binned build) is primary — round 7 A/B proved the direct
    // scattered build (k_fillp) costs 131+ us from write amplification.
    const bool tierA2 = (ws_size >= needA2) && (npb <= NPBMAX) && (N <= (1 << 22)) &&
                        ((size_t)NB * BINCAP <= (size_t)N * H * 2) &&
                        ((size_t)NB * BINCAP >= (size_t)E + E / 4 + 5 * NB);
    const bool tierB  = !tierA2 && (ws_size >= needB) && (B1 <= 1024);
    const bool tierA  = !tierA2 && !tierB && (ws_size >= needA);

    const int* src  = ei;
    const int* dst  = ei + E;
    const int* srcA = eia;
    const int* dstA = eia + EA;

    const int TB = 256;
    const int npool = G * H + G;   // pooled + cnt, contiguous

    k_detect<<<8, 1024, 0, stream>>>(x, 1024, flag, pooled, npool,
                                     tierA2 ? bincur : (tierA ? degA : (int*)nullptr),
                                     tierA2 ? NB * BINSTRIDE : (tierA ? N : 0));

    int ggrid16 = (int)(((long)N * 16 + TB - 1) / TB);
    int ggrid32 = (int)(((long)N * 32 + TB - 1) / TB);
    int ngrid   = (N + TB - 1) / TB;

    if (tierA2) {
        unsigned* binbuf = (unsigned*)A;
        int nblk1 = (E + CHUNK - 1) / CHUNK;
        k_p1<<<nblk1, 1024, 0, stream>>>(src, dst, bincur, binbuf, E, npb);
        k_p2x<<<NB, TB, 0, stream>>>(bincur, binbuf, csrA, degA, dinv,
                                     x, W1, flag, xsb, N, npb);
        k_g1<<<ggrid16, TB, 0, stream>>>(degA, csrA, dinv, xsb, W2, b1, flag, xsb2, N);
        k_g2<<<ggrid16, TB, 0, stream>>>(degA, csrA, dinv, xsb2, b2, Wbil, batch, flag,
                                         pooled, cnt, hb32, gb32, N);
    } else if (tierB) {
        hipMemsetAsync(deg_i, 0, (size_t)N * sizeof(int), stream);
        k_degi<<<(E + TB - 1) / TB, TB, 0, stream>>>(dst, deg_i, E);
        k_dinvi<<<ngrid, TB, 0, stream>>>(deg_i, dinv, N);
        k_scan1<<<B1, TB, 0, stream>>>(deg_i, chunk_off, N);
        k_scan2<<<1, TB, 0, stream>>>(chunk_off, chunk_off, B1);
        k_scan3<<<B1, TB, 0, stream>>>(deg_i, chunk_off, row_ptr, curB, N, E);
        k_fill<<<(E + TB - 1) / TB, TB, 0, stream>>>(src, dst, curB, csrB, E);
        k_xw1n<<<ngrid, TB, 0, stream>>>(x, W1, dinv, flag, A, N);
        k_gather<<<ggrid32, TB, 0, stream>>>(row_ptr, csrB, dinv, A, B, N);
        k_h1xw2n<<<ngrid, TB, 0, stream>>>(W2, b1, dinv, flag, B, A, N);
        k_gather<<<ggrid32, TB, 0, stream>>>(row_ptr, csrB, dinv, A, B, N);
        k_poolhb<<<(N + POOLBLK - 1) / POOLBLK, 512, 0, stream>>>(
            b2, Wbil, batch, flag, B, pooled, cnt, (bf16*)hb32, (bf16*)gb32, N);
    } else if (tierA) {
        k_fillp<<<(E + TB - 1) / TB, TB, 0, stream>>>(src, dst, degA, csrA, E);
        k_dinvi<<<ngrid, TB, 0, stream>>>(degA, dinv, N);
        k_xw1v<<<ggrid16, TB, 0, stream>>>(x, W1, dinv, flag, xsb, N);
        k_g1<<<ggrid16, TB, 0, stream>>>(degA, csrA, dinv, xsb, W2, b1, flag, xsb2, N);
        k_g2<<<ggrid16, TB, 0, stream>>>(degA, csrA, dinv, xsb2, b2, Wbil, batch, flag,
                                         pooled, cnt, hb32, gb32, N);
    } else {
        hipMemsetAsync(dinv, 0, (size_t)N * sizeof(float), stream);
        k_degf<<<(E + TB - 1) / TB, TB, 0, stream>>>(dst, dinv, E);
        k_dinvf<<<ngrid, TB, 0, stream>>>(dinv, N);
        k_xw1o<<<ngrid, TB, 0, stream>>>(x, W1, dinv, flag, A, B, N);
        long tot = (long)E * 32;
        int sgrid = (int)((tot + TB - 1) / TB);
        k_scatter<<<sgrid, TB, 0, stream>>>(src, dst, dinv, A, B, E);
        k_h1xw2o<<<ngrid, TB, 0, stream>>>(W2, b1, dinv, flag, B, A, N);
        k_scatter<<<sgrid, TB, 0, stream>>>(src, dst, dinv, A, B, E);
        k_poolhb<<<(N + POOLBLK - 1) / POOLBLK, 512, 0, stream>>>(
            b2, Wbil, batch, flag, B, pooled, cnt, (bf16*)hb32, (bf16*)gb32, N);
    }

    k_bilreg<<<(EA + G + TB - 1) / TB, TB, 0, stream>>>(
        srcA, dstA, gb32, hb32, bbil, pooled, cnt, Wr, br, flag, d_out, G, EA);
}

// Round 9
// 261.612 us; speedup vs baseline: 1.3181x; 1.0854x over previous
//
#include <hip/hip_runtime.h>
#include <hip/hip_bf16.h>
#include <string.h>
#include <stdint.h>

typedef __hip_bfloat16 bf16;

#define FIN 16
#define H   32
#define PADW 64
#define NB  1024
#define BINCAP 2048
#define NPBMAX 104
#define PSTRIDE 65
#define CHUNK 2048
#define BINSTRIDE 16
#define SCAN_CHUNK 1024
#define MAXSEG 64
#define POOLBLK 256

typedef int vi4 __attribute__((ext_vector_type(4)));

__device__ __forceinline__ float b2f(bf16 v) { return __bfloat162float(v); }

__device__ __forceinline__ float loadf(const void* p, size_t i, int f32) {
    return f32 ? ((const float*)p)[i] : b2f(((const bf16*)p)[i]);
}
__device__ __forceinline__ void storef(void* p, size_t i, float v, int f32) {
    if (f32) ((float*)p)[i] = v;
    else     ((bf16*)p)[i] = __float2bfloat16(v);
}

__device__ __forceinline__ unsigned pack2(float lo, float hi) {
    bf16 a = __float2bfloat16(lo), b = __float2bfloat16(hi);
    unsigned short ua, ub;
    memcpy(&ua, &a, 2); memcpy(&ub, &b, 2);
    return ((unsigned)ub << 16) | (unsigned)ua;
}
__device__ __forceinline__ float f_lo(unsigned u) {
    union { unsigned i; float f; } v; v.i = u << 16; return v.f;
}
__device__ __forceinline__ float f_hi(unsigned u) {
    union { unsigned i; float f; } v; v.i = u & 0xffff0000u; return v.f;
}

// detect (block 0) + grid-stride zero of small buffers (all blocks)
__global__ void k_detect(const void* __restrict__ x, int nelem, int* __restrict__ flag,
                         float* __restrict__ zf, int nzf,
                         int* __restrict__ zi, int nzi) {
    int gt = blockIdx.x * blockDim.x + threadIdx.x;
    int gs = gridDim.x * blockDim.x;
    for (int i = gt; i < nzf; i += gs) zf[i] = 0.f;
    if (zi) for (int i = gt; i < nzi; i += gs) zi[i] = 0;
    if (blockIdx.x != 0) return;
    __shared__ int cntS;
    if (threadIdx.x == 0) cntS = 0;
    __syncthreads();
    int bad = 0;
    const bf16* p = (const bf16*)x;
    for (int i = threadIdx.x; i < nelem; i += blockDim.x) {
        float v = b2f(p[i]);
        float a = fabsf(v);
        if (isnan(v) || a > 1024.f || (v != 0.f && a < 1e-20f)) bad++;
    }
    atomicAdd(&cntS, bad);
    __syncthreads();
    if (threadIdx.x == 0) flag[0] = (cntS > 64) ? 1 : 0;
}

// ---------- Tier A2: two-phase binned padded-CSR build ----------
__global__ void __launch_bounds__(1024) k_p1(
        const int* __restrict__ src, const int* __restrict__ dst,
        int* __restrict__ bincur, unsigned* __restrict__ binbuf,
        int E, int npb) {
    __shared__ int hcnt[4][NB];   // 16 KB
    __shared__ int hbase[NB];
    __shared__ int scur[NB];
    int tid = threadIdx.x;
    int grp = tid >> 8;
    int e0 = blockIdx.x * CHUNK;
    int nE = E - e0;
    if (nE > CHUNK) nE = CHUNK;
    for (int i = tid; i < 4 * NB; i += blockDim.x) ((int*)hcnt)[i] = 0;
    __syncthreads();
    for (int i = tid; i < nE; i += blockDim.x)
        atomicAdd(&hcnt[grp][dst[e0 + i] / npb], 1);
    __syncthreads();
    for (int i = tid; i < NB; i += blockDim.x) {
        int c = hcnt[0][i] + hcnt[1][i] + hcnt[2][i] + hcnt[3][i];
        hbase[i] = c ? atomicAdd(&bincur[i * BINSTRIDE], c) : 0;
        scur[i] = 0;
    }
    __syncthreads();
    for (int i = tid; i < nE; i += blockDim.x) {
        int d = dst[e0 + i];
        int bin = d / npb;
        int pos = hbase[bin] + atomicAdd(&scur[bin], 1);
        if (pos < BINCAP)
            binbuf[(size_t)bin * BINCAP + pos] =
                ((unsigned)src[e0 + i] << 10) | (unsigned)(d - bin * npb);
    }
}

// p2 slim: LDS scatter -> padded CSR rows + deg/dinv only (xw1 de-fused).
// LDS ~27KB, low VGPR -> ~5 blocks/CU (round-8 fused version: 216 VGPR, 6% occ)
__global__ void __launch_bounds__(256) k_p2s(
        const int* __restrict__ bincur, const unsigned* __restrict__ binbuf,
        int* __restrict__ csr, int* __restrict__ deg, float* __restrict__ dinv,
        int N, int npb) {
    __shared__ int cur[NPBMAX];
    __shared__ int psr[NPBMAX * PSTRIDE];   // ~26.4 KB
    int b = blockIdx.x;
    int base = b * npb;
    int nn = N - base;
    if (nn > npb) nn = npb;
    if (nn < 0) nn = 0;
    for (int i = threadIdx.x; i < nn; i += blockDim.x) cur[i] = 0;
    __syncthreads();
    int cnt = bincur[b * BINSTRIDE];
    if (cnt > BINCAP) cnt = BINCAP;
    const unsigned* buf = binbuf + (size_t)b * BINCAP;
    for (int j = threadIdx.x; j < cnt; j += blockDim.x) {
        unsigned p = buf[j];
        int loc = (int)(p & 1023u);
        int s = (int)(p >> 10);
        int pos = atomicAdd(&cur[loc], 1);
        if (pos < PADW) psr[loc * PSTRIDE + pos] = s;
    }
    __syncthreads();
    // vectorized CSR store: int4 chunks; positions >= deg are garbage but
    // never read (gather clamps to deg)
    int tot4 = nn * 16;
    for (int idx = threadIdx.x; idx < tot4; idx += blockDim.x) {
        int i = idx >> 4, p4 = (idx & 15) << 2;
        int dg = cur[i];
        if (dg > PADW) dg = PADW;
        if (p4 < dg) {
            const int* pr = &psr[i * PSTRIDE + p4];
            vi4 v = {pr[0], pr[1], pr[2], pr[3]};
            *(vi4*)(csr + ((size_t)(base + i) << 6) + p4) = v;
        }
    }
    for (int i = threadIdx.x; i < nn; i += blockDim.x) {
        int dg = cur[i];
        deg[base + i] = dg;
        dinv[base + i] = rsqrtf((float)dg + 1.0f);
    }
}

// ---------- Tier A: direct padded CSR (fallback build; known slow) ----------

__global__ void k_fillp(const int* __restrict__ src, const int* __restrict__ dst,
                        int* __restrict__ cursor, int* __restrict__ csr, int E) {
    int e = blockIdx.x * blockDim.x + threadIdx.x;
    if (e >= E) return;
    int d = dst[e];
    int pos = atomicAdd(&cursor[d], 1);
    if (pos < PADW) csr[((size_t)d << 6) + pos] = src[e];
}

__global__ void k_dinvi(const int* __restrict__ deg, float* __restrict__ dinv, int N) {
    int t = blockIdx.x * blockDim.x + threadIdx.x;
    if (t < N) dinv[t] = rsqrtf((float)deg[t] + 1.0f);
}

// xw1: 16 lanes/node, full occupancy (6250 blocks at N=100K)
__global__ void __launch_bounds__(256) k_xw1v(
        const void* __restrict__ x, const void* __restrict__ W1,
        const float* __restrict__ dinv, const int* __restrict__ flag,
        unsigned* __restrict__ xsb, int N) {
    __shared__ float sW[FIN * H];
    __shared__ float sxx[16 * 17];
    int f32 = flag[0];
    for (int i = threadIdx.x; i < FIN * H; i += blockDim.x) sW[i] = loadf(W1, i, f32);
    __syncthreads();
    int t = blockIdx.x * blockDim.x + threadIdx.x;
    int n = t >> 4, j = t & 15, g = threadIdx.x >> 4;
    if (n < N) sxx[g * 17 + j] = loadf(x, (size_t)n * FIN + j, f32);
    __syncthreads();
    if (n >= N) return;
    float dv = dinv[n];
    float s0 = 0.f, s1 = 0.f;
    const float* xp = &sxx[g * 17];
#pragma unroll
    for (int i = 0; i < FIN; i++) {
        float xv = xp[i];
        s0 += xv * sW[i * H + 2 * j];
        s1 += xv * sW[i * H + 2 * j + 1];
    }
    xsb[(size_t)n * 16 + j] = pack2(s0 * dv, s1 * dv);
}

// 8-wide unrolled neighbor accumulation: 8 independent table loads in flight
#define GACC8(TBL)                                                        \
    for (; k + 8 <= len; k += 8) {                                        \
        vi4 sA = *(const vi4*)(lst + k);                                  \
        vi4 sB = *(const vi4*)(lst + k + 4);                              \
        unsigned u0 = TBL[(size_t)sA.x * 16 + j];                         \
        unsigned u1 = TBL[(size_t)sA.y * 16 + j];                         \
        unsigned u2 = TBL[(size_t)sA.z * 16 + j];                         \
        unsigned u3 = TBL[(size_t)sA.w * 16 + j];                         \
        unsigned u4 = TBL[(size_t)sB.x * 16 + j];                         \
        unsigned u5 = TBL[(size_t)sB.y * 16 + j];                         \
        unsigned u6 = TBL[(size_t)sB.z * 16 + j];                         \
        unsigned u7 = TBL[(size_t)sB.w * 16 + j];                         \
        a0 += f_lo(u0); a1 += f_hi(u0);                                   \
        b0 += f_lo(u1); b1v += f_hi(u1);                                  \
        a0 += f_lo(u2); a1 += f_hi(u2);                                   \
        b0 += f_lo(u3); b1v += f_hi(u3);                                  \
        a0 += f_lo(u4); a1 += f_hi(u4);                                   \
        b0 += f_lo(u5); b1v += f_hi(u5);                                  \
        a0 += f_lo(u6); a1 += f_hi(u6);                                   \
        b0 += f_lo(u7); b1v += f_hi(u7);                                  \
    }                                                                     \
    for (; k + 4 <= len; k += 4) {                                        \
        vi4 s4 = *(const vi4*)(lst + k);                                  \
        unsigned u0 = TBL[(size_t)s4.x * 16 + j];                         \
        unsigned u1 = TBL[(size_t)s4.y * 16 + j];                         \
        unsigned u2 = TBL[(size_t)s4.z * 16 + j];                         \
        unsigned u3 = TBL[(size_t)s4.w * 16 + j];                         \
        a0 += f_lo(u0); a1 += f_hi(u0);                                   \
        b0 += f_lo(u1); b1v += f_hi(u1);                                  \
        a0 += f_lo(u2); a1 += f_hi(u2);                                   \
        b0 += f_lo(u3); b1v += f_hi(u3);                                  \
    }                                                                     \
    for (; k < len; k++) {                                                \
        unsigned u2 = TBL[(size_t)lst[k] * 16 + j];                       \
        a0 += f_lo(u2); a1 += f_hi(u2);                                   \
    }

// fused gather #1
__global__ void __launch_bounds__(256) k_g1(
        const int* __restrict__ deg, const int* __restrict__ csr,
        const float* __restrict__ dinv, const unsigned* __restrict__ xsb,
        const void* __restrict__ W2, const void* __restrict__ b1,
        const int* __restrict__ flag, unsigned* __restrict__ xsb2, int N) {
    __shared__ float sW[H * H];
    __shared__ float sb[H];
    __shared__ float shh[16 * 34];
    int f32 = flag[0];
    for (int i = threadIdx.x; i < H * H; i += blockDim.x) sW[i] = loadf(W2, i, f32);
    if (threadIdx.x < H) sb[threadIdx.x] = loadf(b1, threadIdx.x, f32);
    __syncthreads();
    int t = blockIdx.x * blockDim.x + threadIdx.x;
    int d = t >> 4, j = t & 15, g = threadIdx.x >> 4;
    float dv = 0.f;
    if (d < N) {
        int len = deg[d];
        if (len > PADW) len = PADW;
        dv = dinv[d];
        const int* lst = csr + ((size_t)d << 6);
        unsigned u = xsb[(size_t)d * 16 + j];
        float a0 = f_lo(u), a1 = f_hi(u);
        float b0 = 0.f, b1v = 0.f;
        int k = 0;
        GACC8(xsb)
        float h0 = (a0 + b0) * dv + sb[2 * j];
        float h1 = (a1 + b1v) * dv + sb[2 * j + 1];
        shh[g * 34 + 2 * j]     = h0 > 0.f ? h0 : 0.f;
        shh[g * 34 + 2 * j + 1] = h1 > 0.f ? h1 : 0.f;
    }
    __syncthreads();
    if (d >= N) return;
    float s0 = 0.f, s1 = 0.f;
    const float* hp = &shh[g * 34];
#pragma unroll
    for (int i = 0; i < H; i++) {
        float hv = hp[i];
        s0 += hv * sW[i * H + 2 * j];
        s1 += hv * sW[i * H + 2 * j + 1];
    }
    xsb2[(size_t)d * 16 + j] = pack2(s0 * dv, s1 * dv);
}

// fused gather #2
__global__ void __launch_bounds__(256) k_g2(
        const int* __restrict__ deg, const int* __restrict__ csr,
        const float* __restrict__ dinv, const unsigned* __restrict__ xsb2,
        const void* __restrict__ b2v, const void* __restrict__ Wbil,
        const int* __restrict__ batch, const int* __restrict__ flag,
        float* __restrict__ pooled, float* __restrict__ cnt,
        unsigned* __restrict__ hb, unsigned* __restrict__ gb, int N) {
    __shared__ float sW[H * H];
    __shared__ float sb[H];
    __shared__ float shh[16 * 34];
    __shared__ int   sg[16];
    __shared__ float spool[16 * H];
    __shared__ float scnt[16];
    int f32 = flag[0];
    int tid = threadIdx.x;
    for (int i = tid; i < H * H; i += blockDim.x) sW[i] = loadf(Wbil, i, f32);
    if (tid < H) sb[tid] = loadf(b2v, tid, f32);
    for (int i = tid; i < 16 * H; i += blockDim.x) spool[i] = 0.f;
    if (tid < 16) scnt[tid] = 0.f;
    int blk0 = blockIdx.x * 16;
    int nv = N - blk0;
    if (nv > 16) nv = 16;
    if (tid < nv) sg[tid] = batch[blk0 + tid];
    __syncthreads();
    int d = blk0 + (tid >> 4), j = tid & 15, g = tid >> 4;
    float h0 = 0.f, h1 = 0.f;
    int valid = (g < nv);
    if (valid) {
        int len = deg[d];
        if (len > PADW) len = PADW;
        float dv = dinv[d];
        const int* lst = csr + ((size_t)d << 6);
        unsigned u = xsb2[(size_t)d * 16 + j];
        float a0 = f_lo(u), a1 = f_hi(u);
        float b0 = 0.f, b1v = 0.f;
        int k = 0;
        GACC8(xsb2)
        h0 = (a0 + b0) * dv + sb[2 * j];
        h1 = (a1 + b1v) * dv + sb[2 * j + 1];
        hb[(size_t)d * 16 + j] = pack2(h0, h1);
        shh[g * 34 + 2 * j]     = h0;
        shh[g * 34 + 2 * j + 1] = h1;
    }
    int g0 = sg[0];
    int nseg = sg[nv - 1] - g0 + 1;
    if (valid) {
        int sgn = sg[g];
        if (nseg <= 16) {
            atomicAdd(&spool[(sgn - g0) * H + 2 * j], h0);
            atomicAdd(&spool[(sgn - g0) * H + 2 * j + 1], h1);
            if (j == 0) atomicAdd(&scnt[sgn - g0], 1.f);
        } else {
            atomicAdd(&pooled[(size_t)sgn * H + 2 * j], h0);
            atomicAdd(&pooled[(size_t)sgn * H + 2 * j + 1], h1);
            if (j == 0) atomicAdd(&cnt[sgn], 1.f);
        }
    }
    __syncthreads();
    if (nseg <= 16) {
        for (int i = tid; i < nseg * H; i += blockDim.x) {
            float v = spool[i];
            if (v != 0.f) atomicAdd(&pooled[(size_t)(g0 + (i >> 5)) * H + (i & 31)], v);
        }
        for (int i = tid; i < nseg; i += blockDim.x)
            if (scnt[i] != 0.f) atomicAdd(&cnt[g0 + i], scnt[i]);
    }
    if (!valid) return;
    float s0 = 0.f, s1 = 0.f;
    const float* hp = &shh[g * 34];
#pragma unroll
    for (int i = 0; i < H; i++) {
        float hv = hp[i];
        s0 += hv * sW[i * H + 2 * j];
        s1 += hv * sW[i * H + 2 * j + 1];
    }
    gb[(size_t)d * 16 + j] = pack2(s0, s1);
}

// legacy fused pool (tiers B/C)
__global__ void __launch_bounds__(512) k_poolhb(
        const void* __restrict__ b2v, const void* __restrict__ Wbil,
        const int* __restrict__ batch, const int* __restrict__ flag,
        const float* __restrict__ aggB, float* __restrict__ pooled,
        float* __restrict__ cnt, bf16* __restrict__ hb, bf16* __restrict__ gb,
        int N) {
    __shared__ float sW[H * H];
    __shared__ float sb[H];
    __shared__ float sh[POOLBLK][H];
    __shared__ int   sg[POOLBLK];
    __shared__ float spool[MAXSEG * H];
    __shared__ float scnt[MAXSEG];
    int f32 = flag[0];
    int tid = threadIdx.x;
    for (int i = tid; i < H * H; i += blockDim.x) sW[i] = loadf(Wbil, i, f32);
    if (tid < H) sb[tid] = loadf(b2v, tid, f32);
    int blk0 = blockIdx.x * POOLBLK;
    int nvalid = N - blk0;
    if (nvalid > POOLBLK) nvalid = POOLBLK;
    if (tid < nvalid) sg[tid] = batch[blk0 + tid];
    for (int i = tid; i < MAXSEG * H; i += blockDim.x) spool[i] = 0.f;
    if (tid < MAXSEG) scnt[tid] = 0.f;
    __syncthreads();
    int f = tid & 31, k = tid >> 5;
    for (int r = k; r < nvalid; r += 16) {
        float v = aggB[(size_t)(blk0 + r) * H + f] + sb[f];
        sh[r][f] = v;
        hb[(size_t)(blk0 + r) * H + f] = __float2bfloat16(v);
    }
    __syncthreads();
    int g0 = sg[0];
    int nseg = sg[nvalid - 1] - g0 + 1;
    if (nseg <= MAXSEG) {
        for (int r = k; r < nvalid; r += 16) {
            int gl = sg[r] - g0;
            atomicAdd(&spool[gl * H + f], sh[r][f]);
            if (f == 0) atomicAdd(&scnt[gl], 1.f);
        }
    } else {
        for (int r = k; r < nvalid; r += 16) {
            atomicAdd(&pooled[(size_t)sg[r] * H + f], sh[r][f]);
            if (f == 0) atomicAdd(&cnt[sg[r]], 1.f);
        }
    }
    for (int r = k; r < nvalid; r += 16) {
        float s = 0.f;
#pragma unroll
        for (int i = 0; i < H; i++) s += sh[r][i] * sW[i * H + f];
        gb[(size_t)(blk0 + r) * H + f] = __float2bfloat16(s);
    }
    if (nseg <= MAXSEG) {
        __syncthreads();
        for (int i = tid; i < nseg * H; i += blockDim.x)
            atomicAdd(&pooled[(size_t)(g0 + (i >> 5)) * H + (i & 31)], spool[i]);
        for (int i = tid; i < nseg; i += blockDim.x)
            atomicAdd(&cnt[g0 + i], scnt[i]);
    }
}

// ---------- Tier B: compact CSR via scans (fp32 path) ----------

__global__ void k_degi(const int* __restrict__ dst, int* __restrict__ deg, int E) {
    int t = blockIdx.x * blockDim.x + threadIdx.x;
    if (t < E) atomicAdd(&deg[dst[t]], 1);
}

__global__ void k_scan1(const int* __restrict__ deg, int* __restrict__ partials, int N) {
    __shared__ int sd[256];
    int base = blockIdx.x * SCAN_CHUNK + threadIdx.x * 4;
    int s = 0;
#pragma unroll
    for (int k = 0; k < 4; k++) { int i = base + k; s += (i < N) ? deg[i] : 0; }
    sd[threadIdx.x] = s;
    __syncthreads();
    for (int off = 128; off > 0; off >>= 1) {
        if (threadIdx.x < off) sd[threadIdx.x] += sd[threadIdx.x + off];
        __syncthreads();
    }
    if (threadIdx.x == 0) partials[blockIdx.x] = sd[0];
}

__global__ void k_scan2(const int* __restrict__ partials, int* __restrict__ chunk_off, int B1) {
    __shared__ int sd[256];
    int t = threadIdx.x;
    int lv[4];
    int s = 0;
#pragma unroll
    for (int k = 0; k < 4; k++) { int i = t * 4 + k; lv[k] = (i < B1) ? partials[i] : 0; s += lv[k]; }
    sd[t] = s;
    __syncthreads();
    int inc = s;
    for (int off = 1; off < 256; off <<= 1) {
        int v = (t >= off) ? sd[t - off] : 0;
        __syncthreads();
        sd[t] += v;
        __syncthreads();
    }
    int run = sd[t] - inc;
#pragma unroll
    for (int k = 0; k < 4; k++) { int i = t * 4 + k; if (i < B1) chunk_off[i] = run; run += lv[k]; }
    if (t == 255) chunk_off[B1] = run;
}

__global__ void k_scan3(const int* __restrict__ deg, const int* __restrict__ chunk_off,
                        int* __restrict__ row_ptr, int* __restrict__ cursor,
                        int N, int E) {
    __shared__ int sd[256];
    int t = threadIdx.x;
    int base = blockIdx.x * SCAN_CHUNK + t * 4;
    int lv[4];
    int s = 0;
#pragma unroll
    for (int k = 0; k < 4; k++) { int i = base + k; lv[k] = (i < N) ? deg[i] : 0; s += lv[k]; }
    sd[t] = s;
    __syncthreads();
    int inc = s;
    for (int off = 1; off < 256; off <<= 1) {
        int v = (t >= off) ? sd[t - off] : 0;
        __syncthreads();
        sd[t] += v;
        __syncthreads();
    }
    int run = chunk_off[blockIdx.x] + sd[t] - inc;
#pragma unroll
    for (int k = 0; k < 4; k++) {
        int i = base + k;
        if (i < N) { row_ptr[i] = run; cursor[i] = run; }
        run += lv[k];
    }
    if (blockIdx.x == 0 && t == 0) row_ptr[N] = E;
}

__global__ void k_fill(const int* __restrict__ src, const int* __restrict__ dst,
                       int* __restrict__ cursor, int* __restrict__ csr, int E) {
    int e = blockIdx.x * blockDim.x + threadIdx.x;
    if (e >= E) return;
    int pos = atomicAdd(&cursor[dst[e]], 1);
    csr[pos] = src[e];
}

__global__ void k_gather(const int* __restrict__ row_ptr, const int* __restrict__ csr,
                         const float* __restrict__ dinv, const float* __restrict__ xs,
                         float* __restrict__ agg, int N) {
    int t = blockIdx.x * blockDim.x + threadIdx.x;
    int d = t >> 5, f = t & 31;
    if (d >= N) return;
    int beg = row_ptr[d], end = row_ptr[d + 1];
    float acc  = xs[(size_t)d * H + f];
    float acc2 = 0.f;
    int j = beg;
    for (; j + 1 < end; j += 2) {
        int s0 = csr[j], s1 = csr[j + 1];
        acc  += xs[(size_t)s0 * H + f];
        acc2 += xs[(size_t)s1 * H + f];
    }
    if (j < end) acc += xs[(size_t)csr[j] * H + f];
    agg[(size_t)d * H + f] = (acc + acc2) * dinv[d];
}

__global__ void k_xw1n(const void* __restrict__ x, const void* __restrict__ W1,
                       const float* __restrict__ dinv, const int* __restrict__ flag,
                       float* __restrict__ xs, int N) {
    __shared__ float sW[FIN * H];
    int f32 = flag[0];
    for (int i = threadIdx.x; i < FIN * H; i += blockDim.x) sW[i] = loadf(W1, i, f32);
    __syncthreads();
    int n = blockIdx.x * blockDim.x + threadIdx.x;
    if (n >= N) return;
    float xr[FIN];
#pragma unroll
    for (int i = 0; i < FIN; i++) xr[i] = loadf(x, (size_t)n * FIN + i, f32);
    float dv = dinv[n];
#pragma unroll
    for (int f = 0; f < H; f++) {
        float s = 0.f;
#pragma unroll
        for (int i = 0; i < FIN; i++) s += xr[i] * sW[i * H + f];
        xs[(size_t)n * H + f] = s * dv;
    }
}

__global__ void k_h1xw2n(const void* __restrict__ W2, const void* __restrict__ b1,
                         const float* __restrict__ dinv, const int* __restrict__ flag,
                         const float* __restrict__ agg, float* __restrict__ xs2, int N) {
    __shared__ float sW[H * H];
    __shared__ float sb[H];
    int f32 = flag[0];
    for (int i = threadIdx.x; i < H * H; i += blockDim.x) sW[i] = loadf(W2, i, f32);
    if (threadIdx.x < H) sb[threadIdx.x] = loadf(b1, threadIdx.x, f32);
    __syncthreads();
    int n = blockIdx.x * blockDim.x + threadIdx.x;
    if (n >= N) return;
    float hr[H];
#pragma unroll
    for (int f = 0; f < H; f++) {
        float v = agg[(size_t)n * H + f] + sb[f];
        hr[f] = v > 0.f ? v : 0.f;
    }
    float dv = dinv[n];
#pragma unroll
    for (int f = 0; f < H; f++) {
        float s = 0.f;
#pragma unroll
        for (int i = 0; i < H; i++) s += hr[i] * sW[i * H + f];
        xs2[(size_t)n * H + f] = s * dv;
    }
}

// ---------- Tier C fallback: scatter path ----------

__global__ void k_degf(const int* __restrict__ dst, float* __restrict__ deg, int E) {
    int t = blockIdx.x * blockDim.x + threadIdx.x;
    if (t < E) atomicAdd(&deg[dst[t]], 1.0f);
}
__global__ void k_dinvf(float* __restrict__ deg, int N) {
    int t = blockIdx.x * blockDim.x + threadIdx.x;
    if (t < N) deg[t] = rsqrtf(deg[t] + 1.0f);
}
__global__ void k_xw1o(const void* __restrict__ x, const void* __restrict__ W1,
                       const float* __restrict__ dinv, const int* __restrict__ flag,
                       float* __restrict__ xw, float* __restrict__ agg, int N) {
    __shared__ float sW[FIN * H];
    int f32 = flag[0];
    for (int i = threadIdx.x; i < FIN * H; i += blockDim.x) sW[i] = loadf(W1, i, f32);
    __syncthreads();
    int n = blockIdx.x * blockDim.x + threadIdx.x;
    if (n >= N) return;
    float xr[FIN];
#pragma unroll
    for (int i = 0; i < FIN; i++) xr[i] = loadf(x, (size_t)n * FIN + i, f32);
    float dv = dinv[n], dv2 = dv * dv;
#pragma unroll
    for (int f = 0; f < H; f++) {
        float s = 0.f;
#pragma unroll
        for (int i = 0; i < FIN; i++) s += xr[i] * sW[i * H + f];
        xw[(size_t)n * H + f]  = s;
        agg[(size_t)n * H + f] = s * dv2;
    }
}
__global__ void k_scatter(const int* __restrict__ src, const int* __restrict__ dst,
                          const float* __restrict__ dinv, const float* __restrict__ xw,
                          float* __restrict__ agg, int E) {
    int t = blockIdx.x * blockDim.x + threadIdx.x;
    int e = t >> 5, f = t & 31;
    if (e >= E) return;
    int s = src[e], d = dst[e];
    float c = dinv[s] * dinv[d];
    atomicAdd(&agg[(size_t)d * H + f], xw[(size_t)s * H + f] * c);
}
__global__ void k_h1xw2o(const void* __restrict__ W2, const void* __restrict__ b1,
                         const float* __restrict__ dinv, const int* __restrict__ flag,
                         float* __restrict__ aggio, float* __restrict__ xw2, int N) {
    __shared__ float sW[H * H];
    __shared__ float sb[H];
    int f32 = flag[0];
    for (int i = threadIdx.x; i < H * H; i += blockDim.x) sW[i] = loadf(W2, i, f32);
    if (threadIdx.x < H) sb[threadIdx.x] = loadf(b1, threadIdx.x, f32);
    __syncthreads();
    int n = blockIdx.x * blockDim.x + threadIdx.x;
    if (n >= N) return;
    float hr[H];
#pragma unroll
    for (int f = 0; f < H; f++) {
        float v = aggio[(size_t)n * H + f] + sb[f];
        hr[f] = v > 0.f ? v : 0.f;
    }
    float dv = dinv[n], dv2 = dv * dv;
#pragma unroll
    for (int f = 0; f < H; f++) {
        float s = 0.f;
#pragma unroll
        for (int i = 0; i < H; i++) s += hr[i] * sW[i * H + f];
        xw2[(size_t)n * H + f]   = s;
        aggio[(size_t)n * H + f] = s * dv2;
    }
}

// ---------- output heads: bilinear edges + reg head in one launch ----------

__global__ void k_bilreg(const int* __restrict__ srcA, const int* __restrict__ dstA,
                         const unsigned* __restrict__ gb32, const unsigned* __restrict__ hb32,
                         const void* __restrict__ bbil,
                         const float* __restrict__ pooled, const float* __restrict__ cnt,
                         const void* __restrict__ Wr, const void* __restrict__ br,
                         const int* __restrict__ flag, void* __restrict__ out,
                         int G, int EA) {
    int f32 = flag[0];
    int t = blockIdx.x * blockDim.x + threadIdx.x;
    if (t < EA) {
        int s = srcA[t], d = dstA[t];
        const uint4* gp = (const uint4*)(gb32 + (size_t)s * (H / 2));
        const uint4* hp = (const uint4*)(hb32 + (size_t)d * (H / 2));
        float acc = 0.f;
#pragma unroll
        for (int kk = 0; kk < 4; kk++) {
            uint4 a = gp[kk], b = hp[kk];
            acc += f_lo(a.x) * f_lo(b.x) + f_hi(a.x) * f_hi(b.x);
            acc += f_lo(a.y) * f_lo(b.y) + f_hi(a.y) * f_hi(b.y);
            acc += f_lo(a.z) * f_lo(b.z) + f_hi(a.z) * f_hi(b.z);
            acc += f_lo(a.w) * f_lo(b.w) + f_hi(a.w) * f_hi(b.w);
        }
        storef(out, (size_t)G + t, acc + loadf(bbil, 0, f32), f32);
    } else {
        int g = t - EA;
        if (g < G) {
            float c = cnt[g];
            c = c > 1.f ? c : 1.f;
            float s = 0.f;
#pragma unroll
            for (int i = 0; i < H; i++) s += pooled[(size_t)g * H + i] * loadf(Wr, i, f32);
            storef(out, g, s / c + loadf(br, 0, f32), f32);
        }
    }
}

extern "C" void kernel_launch(void* const* d_in, const int* in_sizes, int n_in,
                              void* d_out, int out_size, void* d_ws, size_t ws_size,
                              hipStream_t stream) {
    const void* x     = d_in[0];
    const int*  ei    = (const int*)d_in[1];
    const int*  eia   = (const int*)d_in[2];
    const int*  batch = (const int*)d_in[3];
    const void* W1    = d_in[4];
    const void* b1    = d_in[5];
    const void* W2    = d_in[6];
    const void* b2    = d_in[7];
    const void* Wr    = d_in[8];
    const void* br    = d_in[9];
    const void* Wbil  = d_in[10];
    const void* bbil  = d_in[11];

    const int N  = in_sizes[0] / FIN;
    const int E  = in_sizes[1] / 2;
    const int EA = in_sizes[2] / 2;
    const int G  = out_size - EA;

    // float region: flag[16] | dinv[N] | A[N*H] | B[N*H] | pooled[G*H] | cnt[G]
    float* ws     = (float*)d_ws;
    int*   flag   = (int*)ws;
    float* dinv   = ws + 16;
    float* A      = dinv + N;
    float* B      = A + (size_t)N * H;
    float* pooled = B + (size_t)N * H;
    float* cnt    = pooled + (size_t)G * H;
    float* fend   = cnt + G;

    // bf16 tables: xsb in B-lo, xsb2 in B-hi; hb/gb in A (binbuf space, dead)
    unsigned* xsb  = (unsigned*)B;
    unsigned* xsb2 = (unsigned*)B + (size_t)N * 16;
    unsigned* hb32 = (unsigned*)A;
    unsigned* gb32 = hb32 + (size_t)N * (H / 2);

    // Tier A / A2 int region: deg[N] | csr_pad[N*PADW] (16B-aligned) | bincur[NB*BINSTRIDE]
    int* degA   = (int*)fend;
    int* csrA   = (int*)(((uintptr_t)(degA + N) + 15) & ~(uintptr_t)15);
    int* bincur = csrA + (size_t)N * PADW;
    size_t needA  = (size_t)((char*)bincur - (char*)d_ws);
    size_t needA2 = (size_t)((char*)(bincur + NB * BINSTRIDE) - (char*)d_ws);
    // Tier B int region
    const int B1 = (N + SCAN_CHUNK - 1) / SCAN_CHUNK;
    int* deg_i     = (int*)fend;
    int* curB      = deg_i + N;
    int* row_ptr   = curB + N;
    int* chunk_off = row_ptr + N + 1;
    int* csrB      = chunk_off + B1 + 1;
    size_t needB = (size_t)((char*)(csrB + E) - (char*)d_ws);

    const int npb = (N + NB - 1) / NB;
    // Tier A2 (binned build) is primary — round 7 A/B proved the direct
    // scattered build (k_fillp) costs 131+ us from write amplification.
    const bool tierA2 = (ws_size >= needA2) && (npb <= NPBMAX) && (N <= (1 << 22)) &&
                        ((size_t)NB * BINCAP <= (size_t)N * H * 2) &&
                        ((size_t)NB * BINCAP >= (size_t)E + E / 4 + 5 * NB);
    const bool tierB  = !tierA2 && (ws_size >= needB) && (B1 <= 1024);
    const bool tierA  = !tierA2 && !tierB && (ws_size >= needA);

    const int* src  = ei;
    const int* dst  = ei + E;
    const int* srcA = eia;
    const int* dstA = eia + EA;

    const int TB = 256;
    const int npool = G * H + G;   // pooled + cnt, contiguous

    k_detect<<<8, 1024, 0, stream>>>(x, 1024, flag, pooled, npool,
                                     tierA2 ? bincur : (tierA ? degA : (int*)nullptr),
                                     tierA2 ? NB * BINSTRIDE : (tierA ? N : 0));

    int ggrid16 = (int)(((long)N * 16 + TB - 1) / TB);
    int ggrid32 = (int)(((long)N * 32 + TB - 1) / TB);
    int ngrid   = (N + TB - 1) / TB;

    if (tierA2) {
        unsigned* binbuf = (unsigned*)A;
        int nblk1 = (E + CHUNK - 1) / CHUNK;
        k_p1<<<nblk1, 1024, 0, stream>>>(src, dst, bincur, binbuf, E, npb);
        k_p2s<<<NB, TB, 0, stream>>>(bincur, binbuf, csrA, degA, dinv, N, npb);
        k_xw1v<<<ggrid16, TB, 0, stream>>>(x, W1, dinv, flag, xsb, N);
        k_g1<<<ggrid16, TB, 0, stream>>>(degA, csrA, dinv, xsb, W2, b1, flag, xsb2, N);
        k_g2<<<ggrid16, TB, 0, stream>>>(degA, csrA, dinv, xsb2, b2, Wbil, batch, flag,
                                         pooled, cnt, hb32, gb32, N);
    } else if (tierB) {
        hipMemsetAsync(deg_i, 0, (size_t)N * sizeof(int), stream);
        k_degi<<<(E + TB - 1) / TB, TB, 0, stream>>>(dst, deg_i, E);
        k_dinvi<<<ngrid, TB, 0, stream>>>(deg_i, dinv, N);
        k_scan1<<<B1, TB, 0, stream>>>(deg_i, chunk_off, N);
        k_scan2<<<1, TB, 0, stream>>>(chunk_off, chunk_off, B1);
        k_scan3<<<B1, TB, 0, stream>>>(deg_i, chunk_off, row_ptr, curB, N, E);
        k_fill<<<(E + TB - 1) / TB, TB, 0, stream>>>(src, dst, curB, csrB, E);
        k_xw1n<<<ngrid, TB, 0, stream>>>(x, W1, dinv, flag, A, N);
        k_gather<<<ggrid32, TB, 0, stream>>>(row_ptr, csrB, dinv, A, B, N);
        k_h1xw2n<<<ngrid, TB, 0, stream>>>(W2, b1, dinv, flag, B, A, N);
        k_gather<<<ggrid32, TB, 0, stream>>>(row_ptr, csrB, dinv, A, B, N);
        k_poolhb<<<(N + POOLBLK - 1) / POOLBLK, 512, 0, stream>>>(
            b2, Wbil, batch, flag, B, pooled, cnt, (bf16*)hb32, (bf16*)gb32, N);
    } else if (tierA) {
        k_fillp<<<(E + TB - 1) / TB, TB, 0, stream>>>(src, dst, degA, csrA, E);
        k_dinvi<<<ngrid, TB, 0, stream>>>(degA, dinv, N);
        k_xw1v<<<ggrid16, TB, 0, stream>>>(x, W1, dinv, flag, xsb, N);
        k_g1<<<ggrid16, TB, 0, stream>>>(degA, csrA, dinv, xsb, W2, b1, flag, xsb2, N);
        k_g2<<<ggrid16, TB, 0, stream>>>(degA, csrA, dinv, xsb2, b2, Wbil, batch, flag,
                                         pooled, cnt, hb32, gb32, N);
    } else {
        hipMemsetAsync(dinv, 0, (size_t)N * sizeof(float), stream);
        k_degf<<<(E + TB - 1) / TB, TB, 0, stream>>>(dst, dinv, E);
        k_dinvf<<<ngrid, TB, 0, stream>>>(dinv, N);
        k_xw1o<<<ngrid, TB, 0, stream>>>(x, W1, dinv, flag, A, B, N);
        long tot = (long)E * 32;
        int sgrid = (int)((tot + TB - 1) / TB);
        k_scatter<<<sgrid, TB, 0, stream>>>(src, dst, dinv, A, B, E);
        k_h1xw2o<<<ngrid, TB, 0, stream>>>(W2, b1, dinv, flag, B, A, N);
        k_scatter<<<sgrid, TB, 0, stream>>>(src, dst, dinv, A, B, E);
        k_poolhb<<<(N + POOLBLK - 1) / POOLBLK, 512, 0, stream>>>(
            b2, Wbil, batch, flag, B, pooled, cnt, (bf16*)hb32, (bf16*)gb32, N);
    }

    k_bilreg<<<(EA + G + TB - 1) / TB, TB, 0, stream>>>(
        srcA, dstA, gb32, hb32, bbil, pooled, cnt, Wr, br, flag, d_out, G, EA);
}